// Round 1
// baseline (1114.035 us; speedup 1.0000x reference)
//
#include <hip/hip_runtime.h>
#include <cstdint>
#include <cmath>

#define BB   4
#define NK   4000
#define NKP  (BB*NK)      // 16000 keypoints total
#define CH   128
#define HH   240
#define WW   320
#define HWSZ (HH*WW)
#define NPOS 8

// ws layout (bytes):
//   feats/g : 128000*128*4 = 65,536,000   (offset 0)          [in-place reused as g]
//   sfT     : 128*128*4    = 65,536       (offset 65,536,000)
//   draw    : 16000*128*4  = 8,192,000    (offset 65,601,536)
static constexpr size_t OFF_SFT  = 65536000;
static constexpr size_t OFF_DRAW = 65601536;
static constexpr size_t WS_NEED  = 73793536;

// ---------------- K0: transpose sf_w [d][c] -> sfT [c][d] ----------------
__global__ __launch_bounds__(256) void k_prep(const float* __restrict__ sfw,
                                              float* __restrict__ sfT)
{
    int id = blockIdx.x * 256 + threadIdx.x;   // 16384 total
    int cc = id >> 7, dd = id & 127;
    sfT[cc * 128 + dd] = sfw[dd * 128 + cc];
}

// ---------------- K1: per-keypoint offsets + bilinear sampling ----------------
// block = 1 keypoint, 128 threads (thread = channel for patch load & sampling)
__global__ __launch_bounds__(128) void k_sample(
    const float* __restrict__ x,  const float* __restrict__ kp,
    const float* __restrict__ w1, const float* __restrict__ b1,
    const float* __restrict__ w2, const float* __restrict__ b2,
    float* __restrict__ feats)
{
    const int n  = blockIdx.x;        // 0..15999
    const int bi = n / NK;
    const int t  = threadIdx.x;       // 0..127

    __shared__ __align__(16) float patch[CH * 9];
    __shared__ float red[16 * 8];
    __shared__ float o1[16];
    __shared__ float offv[16];

    const float kx  = kp[(size_t)n * 2 + 0];
    const float ky  = kp[(size_t)n * 2 + 1];
    const float kwx = (kx * 0.5f + 0.5f) * (float)(WW - 1);
    const float kwy = (ky * 0.5f + 0.5f) * (float)(HH - 1);
    const int kwlx = (int)kwx;                 // trunc (coords >= 0)
    const int kwly = (int)kwy;
    int cx = (int)((float)kwlx - 0.5f);        // trunc toward zero, matches .astype(int32)
    int cy = (int)((float)kwly - 0.5f);
    cx = min(max(cx, 0), WW - 1 - 3);          // 316
    cy = min(max(cy, 0), HH - 1 - 3);          // 236

    const float* xb = x + ((size_t)bi * CH + t) * HWSZ;   // this thread's channel plane

    // stage 3x3 patch of own channel into LDS
    {
        const float* p0 = xb + cy * WW + cx;
        #pragma unroll
        for (int i = 0; i < 3; ++i) {
            patch[t * 9 + i * 3 + 0] = p0[i * WW + 0];
            patch[t * 9 + i * 3 + 1] = p0[i * WW + 1];
            patch[t * 9 + i * 3 + 2] = p0[i * WW + 2];
        }
    }
    __syncthreads();

    // offset conv partials: thread -> (o = t&15, channel-group g = t>>4), 16 ch each
    {
        const int o = t & 15, g = t >> 4;
        const float4* wp = (const float4*)(w1 + o * 1152 + g * 144);
        const float4* pp = (const float4*)(patch + g * 144);
        float s = 0.f;
        #pragma unroll
        for (int q = 0; q < 36; ++q) {
            float4 wv = wp[q];
            float4 pv = pp[q];
            s = fmaf(wv.x, pv.x, fmaf(wv.y, pv.y, fmaf(wv.z, pv.z, fmaf(wv.w, pv.w, s))));
        }
        red[o * 8 + g] = s;
    }
    __syncthreads();
    if (t < 16) {
        float s = b1[t];
        #pragma unroll
        for (int g = 0; g < 8; ++g) s += red[t * 8 + g];
        o1[t] = fmaxf(s, 0.f);                         // ReLU
    }
    __syncthreads();
    if (t < 16) {
        float s = b2[t];
        #pragma unroll
        for (int j = 0; j < 16; ++j) s = fmaf(o1[j], w2[t * 16 + j], s);
        offv[t] = fminf(fmaxf(s, -80.f), 80.f);        // clip +-max_off (=80)
    }
    __syncthreads();

    // bilinear sampling (zeros padding, align_corners): thread = channel
    #pragma unroll
    for (int p = 0; p < NPOS; ++p) {
        const float px = kwx + offv[p];
        const float py = kwy + offv[8 + p];
        const float x0 = floorf(px), y0 = floorf(py);
        const float wx = px - x0, wy = py - y0;
        float acc = 0.f;
        #pragma unroll
        for (int dy = 0; dy < 2; ++dy) {
            const float yc = y0 + (float)dy;
            const bool vy = (yc >= 0.f) && (yc <= (float)(HH - 1));
            const int  yi = (int)fminf(fmaxf(yc, 0.f), (float)(HH - 1));
            const float wyv = dy ? wy : (1.f - wy);
            #pragma unroll
            for (int dx = 0; dx < 2; ++dx) {
                const float xc = x0 + (float)dx;
                const bool vx = (xc >= 0.f) && (xc <= (float)(WW - 1));
                const int  xi = (int)fminf(fmaxf(xc, 0.f), (float)(WW - 1));
                const float wxv = dx ? wx : (1.f - wx);
                float v = xb[yi * WW + xi];
                v = (vx && vy) ? v : 0.f;
                acc = fmaf(v, wxv * wyv, acc);
            }
        }
        feats[((size_t)n * 8 + p) * CH + t] = acc;     // row-major [n*8+p][c]
    }
}

// ---------------- K2: g = selu(feats @ sf_w^T), in-place on feats ----------------
// M = 128000, N = 128, K = 128. Tile M=64; AT staged transposed in LDS.
__global__ __launch_bounds__(256) void k_sf(float* __restrict__ gbuf,
                                            const float* __restrict__ sfT)
{
    const int m0 = blockIdx.x * 64;
    const int t  = threadIdx.x;
    __shared__ __align__(16) float AT[128 * 68];       // [k][m], padded 64->68

    #pragma unroll
    for (int i = 0; i < 32; ++i) {
        int flat = i * 256 + t;
        int mm = flat >> 7, kk = flat & 127;
        AT[kk * 68 + mm] = gbuf[(size_t)(m0 + mm) * 128 + kk];
    }
    __syncthreads();

    const int tx = t & 31, ty = t >> 5;
    const int d0 = tx * 4, mb = ty * 8;
    float acc[8][4];
    #pragma unroll
    for (int i = 0; i < 8; ++i)
        #pragma unroll
        for (int j = 0; j < 4; ++j) acc[i][j] = 0.f;

    for (int k = 0; k < 128; ++k) {
        float4 a0 = *(const float4*)(AT + k * 68 + mb);
        float4 a1 = *(const float4*)(AT + k * 68 + mb + 4);
        float4 bq = *(const float4*)(sfT + k * 128 + d0);
        float a[8] = {a0.x, a0.y, a0.z, a0.w, a1.x, a1.y, a1.z, a1.w};
        float b4[4] = {bq.x, bq.y, bq.z, bq.w};
        #pragma unroll
        for (int i = 0; i < 8; ++i)
            #pragma unroll
            for (int j = 0; j < 4; ++j)
                acc[i][j] = fmaf(a[i], b4[j], acc[i][j]);
    }

    #pragma unroll
    for (int i = 0; i < 8; ++i) {
        float4 o;
        float* ov = &o.x;
        #pragma unroll
        for (int j = 0; j < 4; ++j) {
            float v = acc[i][j];
            float r = v > 0.f ? v : 1.6732632423543772f * expm1f(v);
            ov[j] = 1.0507009873554805f * r;
        }
        *(float4*)(gbuf + (size_t)(m0 + mb + i) * 128 + d0) = o;
    }
}

// ---------------- K3: descs = G[16000][1024] @ agg_w[1024][128] ----------------
__global__ __launch_bounds__(256) void k_agg(const float* __restrict__ gbuf,
                                             const float* __restrict__ aggw,
                                             float* __restrict__ draw)
{
    const int m0 = blockIdx.x * 64;     // rows of 16000
    const int t  = threadIdx.x;
    __shared__ __align__(16) float AT[128 * 68];

    const int tx = t & 31, ty = t >> 5;
    const int d0 = tx * 4, mb = ty * 8;
    float acc[8][4];
    #pragma unroll
    for (int i = 0; i < 8; ++i)
        #pragma unroll
        for (int j = 0; j < 4; ++j) acc[i][j] = 0.f;

    for (int kc = 0; kc < 8; ++kc) {
        __syncthreads();
        #pragma unroll
        for (int i = 0; i < 32; ++i) {
            int flat = i * 256 + t;
            int mm = flat >> 7, kk = flat & 127;
            AT[kk * 68 + mm] = gbuf[(size_t)(m0 + mm) * 1024 + kc * 128 + kk];
        }
        __syncthreads();
        for (int kk = 0; kk < 128; ++kk) {
            float4 a0 = *(const float4*)(AT + kk * 68 + mb);
            float4 a1 = *(const float4*)(AT + kk * 68 + mb + 4);
            float4 bq = *(const float4*)(aggw + (size_t)(kc * 128 + kk) * 128 + d0);
            float a[8] = {a0.x, a0.y, a0.z, a0.w, a1.x, a1.y, a1.z, a1.w};
            float b4[4] = {bq.x, bq.y, bq.z, bq.w};
            #pragma unroll
            for (int i = 0; i < 8; ++i)
                #pragma unroll
                for (int j = 0; j < 4; ++j)
                    acc[i][j] = fmaf(a[i], b4[j], acc[i][j]);
        }
    }

    #pragma unroll
    for (int i = 0; i < 8; ++i) {
        float4 o = {acc[i][0], acc[i][1], acc[i][2], acc[i][3]};
        *(float4*)(draw + (size_t)(m0 + mb + i) * 128 + d0) = o;
    }
}

// ---------------- K4: L2 normalize rows ----------------
__global__ __launch_bounds__(256) void k_norm(const float* __restrict__ draw,
                                              float* __restrict__ out)
{
    const int t = threadIdx.x;
    const int wv = t >> 6, l = t & 63;
    const int r = blockIdx.x * 4 + wv;
    float v0 = draw[(size_t)r * 128 + l];
    float v1 = draw[(size_t)r * 128 + 64 + l];
    float s = v0 * v0 + v1 * v1;
    #pragma unroll
    for (int m = 32; m; m >>= 1) s += __shfl_xor(s, m);
    float inv = 1.f / fmaxf(sqrtf(s), 1e-12f);
    out[(size_t)r * 128 + l]      = v0 * inv;
    out[(size_t)r * 128 + 64 + l] = v1 * inv;
}

extern "C" void kernel_launch(void* const* d_in, const int* in_sizes, int n_in,
                              void* d_out, int out_size, void* d_ws, size_t ws_size,
                              hipStream_t stream)
{
    const float* x   = (const float*)d_in[0];
    const float* kp  = (const float*)d_in[1];
    const float* w1  = (const float*)d_in[2];
    const float* b1  = (const float*)d_in[3];
    const float* w2  = (const float*)d_in[4];
    const float* b2  = (const float*)d_in[5];
    const float* sfw = (const float*)d_in[6];
    const float* agg = (const float*)d_in[7];
    float* out = (float*)d_out;

    if (ws_size < WS_NEED) return;   // need ~74 MB scratch

    char*  ws    = (char*)d_ws;
    float* feats = (float*)ws;                  // [128000][128], reused in-place as g
    float* sfT   = (float*)(ws + OFF_SFT);      // [128][128]
    float* draw  = (float*)(ws + OFF_DRAW);     // [16000][128]

    k_prep  <<<64,    256, 0, stream>>>(sfw, sfT);
    k_sample<<<NKP,   128, 0, stream>>>(x, kp, w1, b1, w2, b2, feats);
    k_sf    <<<2000,  256, 0, stream>>>(feats, sfT);
    k_agg   <<<250,   256, 0, stream>>>(feats, agg, draw);
    k_norm  <<<4000,  256, 0, stream>>>(draw, out);
}

// Round 2
// 921.889 us; speedup vs baseline: 1.2084x; 1.2084x over previous
//
#include <hip/hip_runtime.h>
#include <cstdint>
#include <cmath>

#define BB   4
#define NK   4000
#define NKP  (BB*NK)      // 16000 keypoints total
#define CH   128
#define HH   240
#define WW   320
#define HWSZ (HH*WW)
#define NPOS 8

// ws layout (bytes):
//   feats/g : 128000*128*4 = 65,536,000   (offset 0)          [in-place reused as g]
//   sfT     : 128*128*4    = 65,536       @ 65,536,000
//   w1T     : 16*9*128*4   = 73,728       @ 65,601,536
//   xcl     : 4*240*320*128*4 = 157,286,400 @ 65,675,264   (channels-last copy of x)
static constexpr size_t OFF_SFT  = 65536000;
static constexpr size_t OFF_W1T  = 65601536;
static constexpr size_t OFF_XCL  = 65675264;
static constexpr size_t WS_FULL  = 222961664;   // with xcl
static constexpr size_t WS_MIN   = 65675264;    // legacy path (no xcl)

// ---------------- K0: transpose sf_w [d][c]->sfT[c][d]; w1 [o][c][k]->w1T[o][k][c] ----
__global__ __launch_bounds__(256) void k_prep(const float* __restrict__ sfw,
                                              const float* __restrict__ w1,
                                              float* __restrict__ sfT,
                                              float* __restrict__ w1T)
{
    int id = blockIdx.x * 256 + threadIdx.x;   // 34816 total
    if (id < 16384) {
        int cc = id >> 7, dd = id & 127;
        sfT[cc * 128 + dd] = sfw[dd * 128 + cc];
    } else {
        int j = id - 16384;                    // < 18432
        int o = j / 1152, r = j % 1152;
        int k = r >> 7, c = r & 127;
        w1T[j] = w1[o * 1152 + c * 9 + k];
    }
}

// ---------------- K0b: NCHW -> NHWC tiled transpose ----------------
// per batch: transpose [128 ch][76800 px] -> [76800 px][128 ch]
__global__ __launch_bounds__(256) void k_tr(const float* __restrict__ x,
                                            float* __restrict__ xcl)
{
    const int b  = blockIdx.z;
    const int c0 = blockIdx.y * 32;
    const int p0 = blockIdx.x * 32;
    const int tx = threadIdx.x;        // 0..31
    const int ty = threadIdx.y;        // 0..7
    __shared__ float tile[32][33];

    #pragma unroll
    for (int i = 0; i < 4; ++i) {
        int c = ty + i * 8;
        tile[c][tx] = x[((size_t)(b * 128 + c0 + c)) * HWSZ + p0 + tx];
    }
    __syncthreads();
    #pragma unroll
    for (int i = 0; i < 4; ++i) {
        int p = ty + i * 8;
        xcl[((size_t)b * HWSZ + p0 + p) * CH + c0 + tx] = tile[tx][p];
    }
}

// ---------------- K1: per-keypoint offsets + bilinear sampling (channels-last) -------
__global__ __launch_bounds__(128) void k_sample_cl(
    const float* __restrict__ xcl, const float* __restrict__ kp,
    const float* __restrict__ w1T, const float* __restrict__ b1,
    const float* __restrict__ w2,  const float* __restrict__ b2,
    float* __restrict__ feats)
{
    const int n  = blockIdx.x;        // 0..15999
    const int bi = n / NK;
    const int t  = threadIdx.x;       // 0..127 = channel

    __shared__ __align__(16) float patch[9 * CH];   // [pixel k][channel c]
    __shared__ float red[16 * 8];
    __shared__ float o1[16];
    __shared__ float offv[16];

    const float kx  = kp[(size_t)n * 2 + 0];
    const float ky  = kp[(size_t)n * 2 + 1];
    const float kwx = (kx * 0.5f + 0.5f) * (float)(WW - 1);
    const float kwy = (ky * 0.5f + 0.5f) * (float)(HH - 1);
    const int kwlx = (int)kwx;
    const int kwly = (int)kwy;
    int cx = (int)((float)kwlx - 0.5f);
    int cy = (int)((float)kwly - 0.5f);
    cx = min(max(cx, 0), WW - 1 - 3);
    cy = min(max(cy, 0), HH - 1 - 3);

    const float* xb = xcl + (size_t)bi * HWSZ * CH;

    // stage 3x3 patch: 9 coalesced 512B reads
    #pragma unroll
    for (int p = 0; p < 9; ++p) {
        const int py = cy + p / 3, px = cx + p % 3;
        patch[p * CH + t] = xb[((size_t)py * WW + px) * CH + t];
    }
    __syncthreads();

    // offset conv partials: thread -> (o = t&15, group g = t>>4), 144 flat elems each
    {
        const int o = t & 15, g = t >> 4;
        const float4* wp = (const float4*)(w1T + o * 1152 + g * 144);
        const float4* pp = (const float4*)(patch + g * 144);
        float s = 0.f;
        #pragma unroll
        for (int q = 0; q < 36; ++q) {
            float4 wv = wp[q];
            float4 pv = pp[q];
            s = fmaf(wv.x, pv.x, fmaf(wv.y, pv.y, fmaf(wv.z, pv.z, fmaf(wv.w, pv.w, s))));
        }
        red[o * 8 + g] = s;
    }
    __syncthreads();
    if (t < 16) {
        float s = b1[t];
        #pragma unroll
        for (int g = 0; g < 8; ++g) s += red[t * 8 + g];
        o1[t] = fmaxf(s, 0.f);
    }
    __syncthreads();
    if (t < 16) {
        float s = b2[t];
        #pragma unroll
        for (int j = 0; j < 16; ++j) s = fmaf(o1[j], w2[t * 16 + j], s);
        offv[t] = fminf(fmaxf(s, -80.f), 80.f);
    }
    __syncthreads();

    #pragma unroll
    for (int p = 0; p < NPOS; ++p) {
        const float px = kwx + offv[p];
        const float py = kwy + offv[8 + p];
        const float x0 = floorf(px), y0 = floorf(py);
        const float wx = px - x0, wy = py - y0;
        float acc = 0.f;
        #pragma unroll
        for (int dy = 0; dy < 2; ++dy) {
            const float yc = y0 + (float)dy;
            const bool vy = (yc >= 0.f) && (yc <= (float)(HH - 1));
            const int  yi = (int)fminf(fmaxf(yc, 0.f), (float)(HH - 1));
            const float wyv = dy ? wy : (1.f - wy);
            #pragma unroll
            for (int dx = 0; dx < 2; ++dx) {
                const float xc = x0 + (float)dx;
                const bool vx = (xc >= 0.f) && (xc <= (float)(WW - 1));
                const int  xi = (int)fminf(fmaxf(xc, 0.f), (float)(WW - 1));
                const float wxv = dx ? wx : (1.f - wx);
                float v = xb[((size_t)yi * WW + xi) * CH + t];
                v = (vx && vy) ? v : 0.f;
                acc = fmaf(v, wxv * wyv, acc);
            }
        }
        feats[((size_t)n * 8 + p) * CH + t] = acc;
    }
}

// ---------------- K1-legacy: channel-major sampling (fallback if ws too small) -------
__global__ __launch_bounds__(128) void k_sample(
    const float* __restrict__ x,  const float* __restrict__ kp,
    const float* __restrict__ w1, const float* __restrict__ b1,
    const float* __restrict__ w2, const float* __restrict__ b2,
    float* __restrict__ feats)
{
    const int n  = blockIdx.x;
    const int bi = n / NK;
    const int t  = threadIdx.x;

    __shared__ __align__(16) float patch[CH * 9];
    __shared__ float red[16 * 8];
    __shared__ float o1[16];
    __shared__ float offv[16];

    const float kx  = kp[(size_t)n * 2 + 0];
    const float ky  = kp[(size_t)n * 2 + 1];
    const float kwx = (kx * 0.5f + 0.5f) * (float)(WW - 1);
    const float kwy = (ky * 0.5f + 0.5f) * (float)(HH - 1);
    const int kwlx = (int)kwx;
    const int kwly = (int)kwy;
    int cx = (int)((float)kwlx - 0.5f);
    int cy = (int)((float)kwly - 0.5f);
    cx = min(max(cx, 0), WW - 1 - 3);
    cy = min(max(cy, 0), HH - 1 - 3);

    const float* xb = x + ((size_t)bi * CH + t) * HWSZ;
    {
        const float* p0 = xb + cy * WW + cx;
        #pragma unroll
        for (int i = 0; i < 3; ++i) {
            patch[t * 9 + i * 3 + 0] = p0[i * WW + 0];
            patch[t * 9 + i * 3 + 1] = p0[i * WW + 1];
            patch[t * 9 + i * 3 + 2] = p0[i * WW + 2];
        }
    }
    __syncthreads();
    {
        const int o = t & 15, g = t >> 4;
        const float4* wp = (const float4*)(w1 + o * 1152 + g * 144);
        const float4* pp = (const float4*)(patch + g * 144);
        float s = 0.f;
        #pragma unroll
        for (int q = 0; q < 36; ++q) {
            float4 wv = wp[q];
            float4 pv = pp[q];
            s = fmaf(wv.x, pv.x, fmaf(wv.y, pv.y, fmaf(wv.z, pv.z, fmaf(wv.w, pv.w, s))));
        }
        red[o * 8 + g] = s;
    }
    __syncthreads();
    if (t < 16) {
        float s = b1[t];
        #pragma unroll
        for (int g = 0; g < 8; ++g) s += red[t * 8 + g];
        o1[t] = fmaxf(s, 0.f);
    }
    __syncthreads();
    if (t < 16) {
        float s = b2[t];
        #pragma unroll
        for (int j = 0; j < 16; ++j) s = fmaf(o1[j], w2[t * 16 + j], s);
        offv[t] = fminf(fmaxf(s, -80.f), 80.f);
    }
    __syncthreads();

    #pragma unroll
    for (int p = 0; p < NPOS; ++p) {
        const float px = kwx + offv[p];
        const float py = kwy + offv[8 + p];
        const float x0 = floorf(px), y0 = floorf(py);
        const float wx = px - x0, wy = py - y0;
        float acc = 0.f;
        #pragma unroll
        for (int dy = 0; dy < 2; ++dy) {
            const float yc = y0 + (float)dy;
            const bool vy = (yc >= 0.f) && (yc <= (float)(HH - 1));
            const int  yi = (int)fminf(fmaxf(yc, 0.f), (float)(HH - 1));
            const float wyv = dy ? wy : (1.f - wy);
            #pragma unroll
            for (int dx = 0; dx < 2; ++dx) {
                const float xc = x0 + (float)dx;
                const bool vx = (xc >= 0.f) && (xc <= (float)(WW - 1));
                const int  xi = (int)fminf(fmaxf(xc, 0.f), (float)(WW - 1));
                const float wxv = dx ? wx : (1.f - wx);
                float v = xb[yi * WW + xi];
                v = (vx && vy) ? v : 0.f;
                acc = fmaf(v, wxv * wyv, acc);
            }
        }
        feats[((size_t)n * 8 + p) * CH + t] = acc;
    }
}

// ---------------- K2: g = selu(feats @ sf_w^T), in-place ----------------
__global__ __launch_bounds__(256) void k_sf(float* __restrict__ gbuf,
                                            const float* __restrict__ sfT)
{
    const int m0 = blockIdx.x * 64;
    const int t  = threadIdx.x;
    __shared__ __align__(16) float AT[128 * 68];

    #pragma unroll
    for (int i = 0; i < 32; ++i) {
        int flat = i * 256 + t;
        int mm = flat >> 7, kk = flat & 127;
        AT[kk * 68 + mm] = gbuf[(size_t)(m0 + mm) * 128 + kk];
    }
    __syncthreads();

    const int tx = t & 31, ty = t >> 5;
    const int d0 = tx * 4, mb = ty * 8;
    float acc[8][4];
    #pragma unroll
    for (int i = 0; i < 8; ++i)
        #pragma unroll
        for (int j = 0; j < 4; ++j) acc[i][j] = 0.f;

    for (int k = 0; k < 128; ++k) {
        float4 a0 = *(const float4*)(AT + k * 68 + mb);
        float4 a1 = *(const float4*)(AT + k * 68 + mb + 4);
        float4 bq = *(const float4*)(sfT + k * 128 + d0);
        float a[8] = {a0.x, a0.y, a0.z, a0.w, a1.x, a1.y, a1.z, a1.w};
        float b4[4] = {bq.x, bq.y, bq.z, bq.w};
        #pragma unroll
        for (int i = 0; i < 8; ++i)
            #pragma unroll
            for (int j = 0; j < 4; ++j)
                acc[i][j] = fmaf(a[i], b4[j], acc[i][j]);
    }

    #pragma unroll
    for (int i = 0; i < 8; ++i) {
        float4 o;
        float* ov = &o.x;
        #pragma unroll
        for (int j = 0; j < 4; ++j) {
            float v = acc[i][j];
            float r = v > 0.f ? v : 1.6732632423543772f * expm1f(v);
            ov[j] = 1.0507009873554805f * r;
        }
        *(float4*)(gbuf + (size_t)(m0 + mb + i) * 128 + d0) = o;
    }
}

// ---------------- K3: descs = G @ agg_w, fused L2-normalize, write out -------------
__global__ __launch_bounds__(256) void k_agg(const float* __restrict__ gbuf,
                                             const float* __restrict__ aggw,
                                             float* __restrict__ out)
{
    const int m0 = blockIdx.x * 64;
    const int t  = threadIdx.x;
    __shared__ __align__(16) float AT[128 * 68];

    const int tx = t & 31, ty = t >> 5;
    const int d0 = tx * 4, mb = ty * 8;
    float acc[8][4];
    #pragma unroll
    for (int i = 0; i < 8; ++i)
        #pragma unroll
        for (int j = 0; j < 4; ++j) acc[i][j] = 0.f;

    for (int kc = 0; kc < 8; ++kc) {
        __syncthreads();
        #pragma unroll
        for (int i = 0; i < 32; ++i) {
            int flat = i * 256 + t;
            int mm = flat >> 7, kk = flat & 127;
            AT[kk * 68 + mm] = gbuf[(size_t)(m0 + mm) * 1024 + kc * 128 + kk];
        }
        __syncthreads();
        for (int kk = 0; kk < 128; ++kk) {
            float4 a0 = *(const float4*)(AT + kk * 68 + mb);
            float4 a1 = *(const float4*)(AT + kk * 68 + mb + 4);
            float4 bq = *(const float4*)(aggw + (size_t)(kc * 128 + kk) * 128 + d0);
            float a[8] = {a0.x, a0.y, a0.z, a0.w, a1.x, a1.y, a1.z, a1.w};
            float b4[4] = {bq.x, bq.y, bq.z, bq.w};
            #pragma unroll
            for (int i = 0; i < 8; ++i)
                #pragma unroll
                for (int j = 0; j < 4; ++j)
                    acc[i][j] = fmaf(a[i], b4[j], acc[i][j]);
        }
    }

    // fused L2 normalize: each row's 128 cols live across the 32 tx lanes
    // (tx = contiguous half-wave lanes; xor-shuffles with mask<32 stay inside)
    #pragma unroll
    for (int i = 0; i < 8; ++i) {
        float s = acc[i][0] * acc[i][0] + acc[i][1] * acc[i][1]
                + acc[i][2] * acc[i][2] + acc[i][3] * acc[i][3];
        #pragma unroll
        for (int m = 16; m; m >>= 1) s += __shfl_xor(s, m);
        const float inv = 1.f / fmaxf(sqrtf(s), 1e-12f);
        float4 o = {acc[i][0] * inv, acc[i][1] * inv, acc[i][2] * inv, acc[i][3] * inv};
        *(float4*)(out + (size_t)(m0 + mb + i) * 128 + d0) = o;
    }
}

extern "C" void kernel_launch(void* const* d_in, const int* in_sizes, int n_in,
                              void* d_out, int out_size, void* d_ws, size_t ws_size,
                              hipStream_t stream)
{
    const float* x   = (const float*)d_in[0];
    const float* kp  = (const float*)d_in[1];
    const float* w1  = (const float*)d_in[2];
    const float* b1  = (const float*)d_in[3];
    const float* w2  = (const float*)d_in[4];
    const float* b2  = (const float*)d_in[5];
    const float* sfw = (const float*)d_in[6];
    const float* agg = (const float*)d_in[7];
    float* out = (float*)d_out;

    if (ws_size < WS_MIN) return;

    char*  ws    = (char*)d_ws;
    float* feats = (float*)ws;                  // [128000][128], reused in-place as g
    float* sfT   = (float*)(ws + OFF_SFT);      // [128][128]
    float* w1T   = (float*)(ws + OFF_W1T);      // [16][9][128]
    float* xcl   = (float*)(ws + OFF_XCL);      // [4][240][320][128]

    k_prep<<<136, 256, 0, stream>>>(sfw, w1, sfT, w1T);

    if (ws_size >= WS_FULL) {
        dim3 grid(HWSZ / 32, CH / 32, BB), blk(32, 8);
        k_tr       <<<grid, blk, 0, stream>>>(x, xcl);
        k_sample_cl<<<NKP, 128, 0, stream>>>(xcl, kp, w1T, b1, w2, b2, feats);
    } else {
        k_sample   <<<NKP, 128, 0, stream>>>(x, kp, w1, b1, w2, b2, feats);
    }

    k_sf <<<2000, 256, 0, stream>>>(feats, sfT);
    k_agg<<<250,  256, 0, stream>>>(feats, agg, out);
}

// Round 3
// 574.772 us; speedup vs baseline: 1.9382x; 1.6039x over previous
//
#include <hip/hip_runtime.h>
#include <cstdint>
#include <cmath>

#define BB   4
#define NK   4000
#define NKP  (BB*NK)      // 16000 keypoints total
#define CH   128
#define HH   240
#define WW   320
#define HWSZ (HH*WW)
#define NPOS 8

// ws layout (bytes):
//   feats/g : 128000*128*4 = 65,536,000   (offset 0)          [in-place reused as g]
//   sfT     : 128*128*4    = 65,536       @ 65,536,000
//   w1T     : 16*9*128*4   = 73,728       @ 65,601,536
//   xcl     : 4*240*320*128*4 = 157,286,400 @ 65,675,264   (channels-last copy of x)
//   part    : aliases xcl region (xcl dead after k_sample_cl): 8*16000*128*4 = 65,536,000
static constexpr size_t OFF_SFT  = 65536000;
static constexpr size_t OFF_W1T  = 65601536;
static constexpr size_t OFF_XCL  = 65675264;
static constexpr size_t WS_FULL  = 222961664;   // with xcl
static constexpr size_t WS_MIN   = 65675264;    // legacy path (no xcl)

// ---------------- K0: transpose sf_w [d][c]->sfT[c][d]; w1 [o][c][k]->w1T[o][k][c] ----
__global__ __launch_bounds__(256) void k_prep(const float* __restrict__ sfw,
                                              const float* __restrict__ w1,
                                              float* __restrict__ sfT,
                                              float* __restrict__ w1T)
{
    int id = blockIdx.x * 256 + threadIdx.x;   // 34816 total
    if (id < 16384) {
        int cc = id >> 7, dd = id & 127;
        sfT[cc * 128 + dd] = sfw[dd * 128 + cc];
    } else {
        int j = id - 16384;                    // < 18432
        int o = j / 1152, r = j % 1152;
        int k = r >> 7, c = r & 127;
        w1T[j] = w1[o * 1152 + c * 9 + k];
    }
}

// ---------------- K0b: NCHW -> NHWC tiled transpose ----------------
__global__ __launch_bounds__(256) void k_tr(const float* __restrict__ x,
                                            float* __restrict__ xcl)
{
    const int b  = blockIdx.z;
    const int c0 = blockIdx.y * 32;
    const int p0 = blockIdx.x * 32;
    const int tx = threadIdx.x;        // 0..31
    const int ty = threadIdx.y;        // 0..7
    __shared__ float tile[32][33];

    #pragma unroll
    for (int i = 0; i < 4; ++i) {
        int c = ty + i * 8;
        tile[c][tx] = x[((size_t)(b * 128 + c0 + c)) * HWSZ + p0 + tx];
    }
    __syncthreads();
    #pragma unroll
    for (int i = 0; i < 4; ++i) {
        int p = ty + i * 8;
        xcl[((size_t)b * HWSZ + p0 + p) * CH + c0 + tx] = tile[tx][p];
    }
}

// ---------------- K1: per-keypoint offsets + bilinear sampling (channels-last) -------
__global__ __launch_bounds__(128) void k_sample_cl(
    const float* __restrict__ xcl, const float* __restrict__ kp,
    const float* __restrict__ w1T, const float* __restrict__ b1,
    const float* __restrict__ w2,  const float* __restrict__ b2,
    float* __restrict__ feats)
{
    const int n  = blockIdx.x;        // 0..15999
    const int bi = n / NK;
    const int t  = threadIdx.x;       // 0..127 = channel

    __shared__ __align__(16) float patch[9 * CH];   // [pixel k][channel c]
    __shared__ float red[16 * 8];
    __shared__ float o1[16];
    __shared__ float offv[16];

    const float kx  = kp[(size_t)n * 2 + 0];
    const float ky  = kp[(size_t)n * 2 + 1];
    const float kwx = (kx * 0.5f + 0.5f) * (float)(WW - 1);
    const float kwy = (ky * 0.5f + 0.5f) * (float)(HH - 1);
    const int kwlx = (int)kwx;
    const int kwly = (int)kwy;
    int cx = (int)((float)kwlx - 0.5f);
    int cy = (int)((float)kwly - 0.5f);
    cx = min(max(cx, 0), WW - 1 - 3);
    cy = min(max(cy, 0), HH - 1 - 3);

    const float* xb = xcl + (size_t)bi * HWSZ * CH;

    #pragma unroll
    for (int p = 0; p < 9; ++p) {
        const int py = cy + p / 3, px = cx + p % 3;
        patch[p * CH + t] = xb[((size_t)py * WW + px) * CH + t];
    }
    __syncthreads();

    {
        const int o = t & 15, g = t >> 4;
        const float4* wp = (const float4*)(w1T + o * 1152 + g * 144);
        const float4* pp = (const float4*)(patch + g * 144);
        float s = 0.f;
        #pragma unroll
        for (int q = 0; q < 36; ++q) {
            float4 wv = wp[q];
            float4 pv = pp[q];
            s = fmaf(wv.x, pv.x, fmaf(wv.y, pv.y, fmaf(wv.z, pv.z, fmaf(wv.w, pv.w, s))));
        }
        red[o * 8 + g] = s;
    }
    __syncthreads();
    if (t < 16) {
        float s = b1[t];
        #pragma unroll
        for (int g = 0; g < 8; ++g) s += red[t * 8 + g];
        o1[t] = fmaxf(s, 0.f);
    }
    __syncthreads();
    if (t < 16) {
        float s = b2[t];
        #pragma unroll
        for (int j = 0; j < 16; ++j) s = fmaf(o1[j], w2[t * 16 + j], s);
        offv[t] = fminf(fmaxf(s, -80.f), 80.f);
    }
    __syncthreads();

    #pragma unroll
    for (int p = 0; p < NPOS; ++p) {
        const float px = kwx + offv[p];
        const float py = kwy + offv[8 + p];
        const float x0 = floorf(px), y0 = floorf(py);
        const float wx = px - x0, wy = py - y0;
        float acc = 0.f;
        #pragma unroll
        for (int dy = 0; dy < 2; ++dy) {
            const float yc = y0 + (float)dy;
            const bool vy = (yc >= 0.f) && (yc <= (float)(HH - 1));
            const int  yi = (int)fminf(fmaxf(yc, 0.f), (float)(HH - 1));
            const float wyv = dy ? wy : (1.f - wy);
            #pragma unroll
            for (int dx = 0; dx < 2; ++dx) {
                const float xc = x0 + (float)dx;
                const bool vx = (xc >= 0.f) && (xc <= (float)(WW - 1));
                const int  xi = (int)fminf(fmaxf(xc, 0.f), (float)(WW - 1));
                const float wxv = dx ? wx : (1.f - wx);
                float v = xb[((size_t)yi * WW + xi) * CH + t];
                v = (vx && vy) ? v : 0.f;
                acc = fmaf(v, wxv * wyv, acc);
            }
        }
        feats[((size_t)n * 8 + p) * CH + t] = acc;
    }
}

// ---------------- K1-legacy: channel-major sampling (fallback if ws too small) -------
__global__ __launch_bounds__(128) void k_sample(
    const float* __restrict__ x,  const float* __restrict__ kp,
    const float* __restrict__ w1, const float* __restrict__ b1,
    const float* __restrict__ w2, const float* __restrict__ b2,
    float* __restrict__ feats)
{
    const int n  = blockIdx.x;
    const int bi = n / NK;
    const int t  = threadIdx.x;

    __shared__ __align__(16) float patch[CH * 9];
    __shared__ float red[16 * 8];
    __shared__ float o1[16];
    __shared__ float offv[16];

    const float kx  = kp[(size_t)n * 2 + 0];
    const float ky  = kp[(size_t)n * 2 + 1];
    const float kwx = (kx * 0.5f + 0.5f) * (float)(WW - 1);
    const float kwy = (ky * 0.5f + 0.5f) * (float)(HH - 1);
    const int kwlx = (int)kwx;
    const int kwly = (int)kwy;
    int cx = (int)((float)kwlx - 0.5f);
    int cy = (int)((float)kwly - 0.5f);
    cx = min(max(cx, 0), WW - 1 - 3);
    cy = min(max(cy, 0), HH - 1 - 3);

    const float* xb = x + ((size_t)bi * CH + t) * HWSZ;
    {
        const float* p0 = xb + cy * WW + cx;
        #pragma unroll
        for (int i = 0; i < 3; ++i) {
            patch[t * 9 + i * 3 + 0] = p0[i * WW + 0];
            patch[t * 9 + i * 3 + 1] = p0[i * WW + 1];
            patch[t * 9 + i * 3 + 2] = p0[i * WW + 2];
        }
    }
    __syncthreads();
    {
        const int o = t & 15, g = t >> 4;
        const float4* wp = (const float4*)(w1 + o * 1152 + g * 144);
        const float4* pp = (const float4*)(patch + g * 144);
        float s = 0.f;
        #pragma unroll
        for (int q = 0; q < 36; ++q) {
            float4 wv = wp[q];
            float4 pv = pp[q];
            s = fmaf(wv.x, pv.x, fmaf(wv.y, pv.y, fmaf(wv.z, pv.z, fmaf(wv.w, pv.w, s))));
        }
        red[o * 8 + g] = s;
    }
    __syncthreads();
    if (t < 16) {
        float s = b1[t];
        #pragma unroll
        for (int g = 0; g < 8; ++g) s += red[t * 8 + g];
        o1[t] = fmaxf(s, 0.f);
    }
    __syncthreads();
    if (t < 16) {
        float s = b2[t];
        #pragma unroll
        for (int j = 0; j < 16; ++j) s = fmaf(o1[j], w2[t * 16 + j], s);
        offv[t] = fminf(fmaxf(s, -80.f), 80.f);
    }
    __syncthreads();

    #pragma unroll
    for (int p = 0; p < NPOS; ++p) {
        const float px = kwx + offv[p];
        const float py = kwy + offv[8 + p];
        const float x0 = floorf(px), y0 = floorf(py);
        const float wx = px - x0, wy = py - y0;
        float acc = 0.f;
        #pragma unroll
        for (int dy = 0; dy < 2; ++dy) {
            const float yc = y0 + (float)dy;
            const bool vy = (yc >= 0.f) && (yc <= (float)(HH - 1));
            const int  yi = (int)fminf(fmaxf(yc, 0.f), (float)(HH - 1));
            const float wyv = dy ? wy : (1.f - wy);
            #pragma unroll
            for (int dx = 0; dx < 2; ++dx) {
                const float xc = x0 + (float)dx;
                const bool vx = (xc >= 0.f) && (xc <= (float)(WW - 1));
                const int  xi = (int)fminf(fmaxf(xc, 0.f), (float)(WW - 1));
                const float wxv = dx ? wx : (1.f - wx);
                float v = xb[yi * WW + xi];
                v = (vx && vy) ? v : 0.f;
                acc = fmaf(v, wxv * wyv, acc);
            }
        }
        feats[((size_t)n * 8 + p) * CH + t] = acc;
    }
}

// ---------------- K2: g = selu(feats @ sf_w^T), in-place ----------------
__global__ __launch_bounds__(256) void k_sf(float* __restrict__ gbuf,
                                            const float* __restrict__ sfT)
{
    const int m0 = blockIdx.x * 64;
    const int t  = threadIdx.x;
    __shared__ __align__(16) float AT[128 * 68];

    #pragma unroll
    for (int i = 0; i < 32; ++i) {
        int flat = i * 256 + t;
        int mm = flat >> 7, kk = flat & 127;
        AT[kk * 68 + mm] = gbuf[(size_t)(m0 + mm) * 128 + kk];
    }
    __syncthreads();

    const int tx = t & 31, ty = t >> 5;
    const int d0 = tx * 4, mb = ty * 8;
    float acc[8][4];
    #pragma unroll
    for (int i = 0; i < 8; ++i)
        #pragma unroll
        for (int j = 0; j < 4; ++j) acc[i][j] = 0.f;

    #pragma unroll 4
    for (int k = 0; k < 128; ++k) {
        float4 a0 = *(const float4*)(AT + k * 68 + mb);
        float4 a1 = *(const float4*)(AT + k * 68 + mb + 4);
        float4 bq = *(const float4*)(sfT + k * 128 + d0);
        float a[8] = {a0.x, a0.y, a0.z, a0.w, a1.x, a1.y, a1.z, a1.w};
        float b4[4] = {bq.x, bq.y, bq.z, bq.w};
        #pragma unroll
        for (int i = 0; i < 8; ++i)
            #pragma unroll
            for (int j = 0; j < 4; ++j)
                acc[i][j] = fmaf(a[i], b4[j], acc[i][j]);
    }

    #pragma unroll
    for (int i = 0; i < 8; ++i) {
        float4 o;
        float* ov = &o.x;
        #pragma unroll
        for (int j = 0; j < 4; ++j) {
            float v = acc[i][j];
            float r = v > 0.f ? v : 1.6732632423543772f * expm1f(v);
            ov[j] = 1.0507009873554805f * r;
        }
        *(float4*)(gbuf + (size_t)(m0 + mb + i) * 128 + d0) = o;
    }
}

// ---------------- K3a: split-K partial GEMM: part[kc] = G[:,kc*128:+128] @ agg_w[kc] --
__global__ __launch_bounds__(256) void k_agg_split(const float* __restrict__ gbuf,
                                                   const float* __restrict__ aggw,
                                                   float* __restrict__ part)
{
    const int m0 = blockIdx.x * 64;     // 250 m-tiles
    const int kc = blockIdx.y;          // 8 K-chunks
    const int t  = threadIdx.x;
    __shared__ __align__(16) float AT[128 * 68];

    #pragma unroll
    for (int i = 0; i < 32; ++i) {
        int flat = i * 256 + t;
        int mm = flat >> 7, kk = flat & 127;
        AT[kk * 68 + mm] = gbuf[(size_t)(m0 + mm) * 1024 + kc * 128 + kk];
    }
    __syncthreads();

    const int tx = t & 31, ty = t >> 5;
    const int d0 = tx * 4, mb = ty * 8;
    float acc[8][4];
    #pragma unroll
    for (int i = 0; i < 8; ++i)
        #pragma unroll
        for (int j = 0; j < 4; ++j) acc[i][j] = 0.f;

    const float* bp = aggw + (size_t)kc * 128 * 128;
    #pragma unroll 4
    for (int kk = 0; kk < 128; ++kk) {
        float4 a0 = *(const float4*)(AT + kk * 68 + mb);
        float4 a1 = *(const float4*)(AT + kk * 68 + mb + 4);
        float4 bq = *(const float4*)(bp + (size_t)kk * 128 + d0);
        float a[8] = {a0.x, a0.y, a0.z, a0.w, a1.x, a1.y, a1.z, a1.w};
        float b4[4] = {bq.x, bq.y, bq.z, bq.w};
        #pragma unroll
        for (int i = 0; i < 8; ++i)
            #pragma unroll
            for (int j = 0; j < 4; ++j)
                acc[i][j] = fmaf(a[i], b4[j], acc[i][j]);
    }

    #pragma unroll
    for (int i = 0; i < 8; ++i) {
        float4 o = {acc[i][0], acc[i][1], acc[i][2], acc[i][3]};
        *(float4*)(part + ((size_t)kc * NKP + m0 + mb + i) * 128 + d0) = o;
    }
}

// ---------------- K3b: reduce 8 partials + L2 normalize ----------------
__global__ __launch_bounds__(256) void k_rn(const float* __restrict__ part,
                                            float* __restrict__ out)
{
    const int t = threadIdx.x;
    const int wv = t >> 6, l = t & 63;
    const int r = blockIdx.x * 4 + wv;
    float v0 = 0.f, v1 = 0.f;
    #pragma unroll
    for (int kc = 0; kc < 8; ++kc) {
        v0 += part[((size_t)kc * NKP + r) * 128 + l];
        v1 += part[((size_t)kc * NKP + r) * 128 + 64 + l];
    }
    float s = v0 * v0 + v1 * v1;
    #pragma unroll
    for (int m = 32; m; m >>= 1) s += __shfl_xor(s, m);
    float inv = 1.f / fmaxf(sqrtf(s), 1e-12f);
    out[(size_t)r * 128 + l]      = v0 * inv;
    out[(size_t)r * 128 + 64 + l] = v1 * inv;
}

// ---------------- K3-legacy: monolithic agg + fused norm (fallback path) -----------
__global__ __launch_bounds__(256) void k_agg_mono(const float* __restrict__ gbuf,
                                                  const float* __restrict__ aggw,
                                                  float* __restrict__ out)
{
    const int m0 = blockIdx.x * 64;
    const int t  = threadIdx.x;
    __shared__ __align__(16) float AT[128 * 68];

    const int tx = t & 31, ty = t >> 5;
    const int d0 = tx * 4, mb = ty * 8;
    float acc[8][4];
    #pragma unroll
    for (int i = 0; i < 8; ++i)
        #pragma unroll
        for (int j = 0; j < 4; ++j) acc[i][j] = 0.f;

    for (int kc = 0; kc < 8; ++kc) {
        __syncthreads();
        #pragma unroll
        for (int i = 0; i < 32; ++i) {
            int flat = i * 256 + t;
            int mm = flat >> 7, kk = flat & 127;
            AT[kk * 68 + mm] = gbuf[(size_t)(m0 + mm) * 1024 + kc * 128 + kk];
        }
        __syncthreads();
        #pragma unroll 4
        for (int kk = 0; kk < 128; ++kk) {
            float4 a0 = *(const float4*)(AT + kk * 68 + mb);
            float4 a1 = *(const float4*)(AT + kk * 68 + mb + 4);
            float4 bq = *(const float4*)(aggw + (size_t)(kc * 128 + kk) * 128 + d0);
            float a[8] = {a0.x, a0.y, a0.z, a0.w, a1.x, a1.y, a1.z, a1.w};
            float b4[4] = {bq.x, bq.y, bq.z, bq.w};
            #pragma unroll
            for (int i = 0; i < 8; ++i)
                #pragma unroll
                for (int j = 0; j < 4; ++j)
                    acc[i][j] = fmaf(a[i], b4[j], acc[i][j]);
        }
    }

    #pragma unroll
    for (int i = 0; i < 8; ++i) {
        float s = acc[i][0] * acc[i][0] + acc[i][1] * acc[i][1]
                + acc[i][2] * acc[i][2] + acc[i][3] * acc[i][3];
        #pragma unroll
        for (int m = 16; m; m >>= 1) s += __shfl_xor(s, m);
        const float inv = 1.f / fmaxf(sqrtf(s), 1e-12f);
        float4 o = {acc[i][0] * inv, acc[i][1] * inv, acc[i][2] * inv, acc[i][3] * inv};
        *(float4*)(out + (size_t)(m0 + mb + i) * 128 + d0) = o;
    }
}

extern "C" void kernel_launch(void* const* d_in, const int* in_sizes, int n_in,
                              void* d_out, int out_size, void* d_ws, size_t ws_size,
                              hipStream_t stream)
{
    const float* x   = (const float*)d_in[0];
    const float* kp  = (const float*)d_in[1];
    const float* w1  = (const float*)d_in[2];
    const float* b1  = (const float*)d_in[3];
    const float* w2  = (const float*)d_in[4];
    const float* b2  = (const float*)d_in[5];
    const float* sfw = (const float*)d_in[6];
    const float* agg = (const float*)d_in[7];
    float* out = (float*)d_out;

    if (ws_size < WS_MIN) return;

    char*  ws    = (char*)d_ws;
    float* feats = (float*)ws;                  // [128000][128], reused in-place as g
    float* sfT   = (float*)(ws + OFF_SFT);      // [128][128]
    float* w1T   = (float*)(ws + OFF_W1T);      // [16][9][128]
    float* xcl   = (float*)(ws + OFF_XCL);      // [4][240][320][128]; reused as part[8][16000][128]

    k_prep<<<136, 256, 0, stream>>>(sfw, w1, sfT, w1T);

    if (ws_size >= WS_FULL) {
        dim3 grid(HWSZ / 32, CH / 32, BB), blk(32, 8);
        k_tr       <<<grid, blk, 0, stream>>>(x, xcl);
        k_sample_cl<<<NKP, 128, 0, stream>>>(xcl, kp, w1T, b1, w2, b2, feats);
        k_sf       <<<2000, 256, 0, stream>>>(feats, sfT);
        dim3 ag(250, 8);
        k_agg_split<<<ag,   256, 0, stream>>>(feats, agg, xcl);   // xcl region = partials
        k_rn       <<<4000, 256, 0, stream>>>(xcl, out);
    } else {
        k_sample   <<<NKP, 128, 0, stream>>>(x, kp, w1, b1, w2, b2, feats);
        k_sf       <<<2000, 256, 0, stream>>>(feats, sfT);
        k_agg_mono <<<250,  256, 0, stream>>>(feats, agg, out);
    }
}

// Round 4
// 487.385 us; speedup vs baseline: 2.2857x; 1.1793x over previous
//
#include <hip/hip_runtime.h>
#include <cstdint>
#include <cmath>

#define BB   4
#define NK   4000
#define NKP  (BB*NK)      // 16000 keypoints total
#define CH   128
#define HH   240
#define WW   320
#define HWSZ (HH*WW)
#define NPOS 8

typedef __attribute__((ext_vector_type(8))) short short8;
typedef __attribute__((ext_vector_type(4))) float f32x4;

// ws layout (bytes):
//   feats/g : 128000*128*4 = 65,536,000  @ 0          [in-place reused as g]
//   sfT     : 128*128*4    = 65,536      @ 65,536,000 [legacy path only]
//   w1T     : 16*9*128*4   = 73,728      @ 65,601,536
//   xcl     : 157,286,400               @ 65,675,264  [NHWC x; reused as part[8][16000][128]]
//   sfB     : 16384*2      = 32,768      @ 222,961,664 [bf16 MFMA-packed sf_w^T]
//   agB     : 131072*2     = 262,144     @ 222,994,432 [bf16 MFMA-packed agg_w]
static constexpr size_t OFF_SFT  = 65536000;
static constexpr size_t OFF_W1T  = 65601536;
static constexpr size_t OFF_XCL  = 65675264;
static constexpr size_t OFF_SFB  = 222961664;
static constexpr size_t OFF_AGB  = 222994432;
static constexpr size_t WS_FULL  = 223256576;
static constexpr size_t WS_MIN   = 65675264;

__device__ __forceinline__ unsigned short f2bf(float f) {   // RNE
    unsigned int u = __float_as_uint(f);
    u += 0x7fff + ((u >> 16) & 1);
    return (unsigned short)(u >> 16);
}

// ---------------- K0: weight prep ----------------
// sfT[c][d] (fp32, legacy) ; w1T[o][k][c] ; sfB/agB bf16 packed in MFMA B-fragment
// order: idx = ((kc32*8 + nt)*64 + lane)*8 + j  ->  B[k = kc32*32+(lane>>4)*8+j][n = nt*16+(lane&15)]
__global__ __launch_bounds__(256) void k_prep(const float* __restrict__ sfw,
                                              const float* __restrict__ w1,
                                              const float* __restrict__ aggw,
                                              float* __restrict__ sfT,
                                              float* __restrict__ w1T,
                                              unsigned short* __restrict__ sfB,
                                              unsigned short* __restrict__ agB)
{
    int id = blockIdx.x * 256 + threadIdx.x;   // 182272 total
    if (id < 16384) {
        int cc = id >> 7, dd = id & 127;
        sfT[cc * 128 + dd] = sfw[dd * 128 + cc];
    } else if (id < 16384 + 18432) {
        int j = id - 16384;
        int o = j / 1152, r = j % 1152;
        int k = r >> 7, c = r & 127;
        w1T[j] = w1[o * 1152 + c * 9 + k];
    } else if (id < 16384 + 18432 + 16384) {
        int idx = id - (16384 + 18432);
        int j = idx & 7, lane = (idx >> 3) & 63, nt = (idx >> 9) & 7, kc32 = (idx >> 12) & 3;
        int k = kc32 * 32 + (lane >> 4) * 8 + j;
        int n = nt * 16 + (lane & 15);
        sfB[idx] = f2bf(sfw[n * 128 + k]);     // B[c][d] = sf_w[d][c]
    } else if (id < 16384 + 18432 + 16384 + 131072) {
        int idx = id - (16384 + 18432 + 16384);
        int local = idx & 16383, kc = idx >> 14;
        int j = local & 7, lane = (local >> 3) & 63, nt = (local >> 9) & 7, kc32 = (local >> 12) & 3;
        int k = kc * 128 + kc32 * 32 + (lane >> 4) * 8 + j;
        int n = nt * 16 + (lane & 15);
        agB[idx] = f2bf(aggw[(size_t)k * 128 + n]);
    }
}

// ---------------- K0b: NCHW -> NHWC tiled transpose ----------------
__global__ __launch_bounds__(256) void k_tr(const float* __restrict__ x,
                                            float* __restrict__ xcl)
{
    const int b  = blockIdx.z;
    const int c0 = blockIdx.y * 32;
    const int p0 = blockIdx.x * 32;
    const int tx = threadIdx.x;
    const int ty = threadIdx.y;
    __shared__ float tile[32][33];

    #pragma unroll
    for (int i = 0; i < 4; ++i) {
        int c = ty + i * 8;
        tile[c][tx] = x[((size_t)(b * 128 + c0 + c)) * HWSZ + p0 + tx];
    }
    __syncthreads();
    #pragma unroll
    for (int i = 0; i < 4; ++i) {
        int p = ty + i * 8;
        xcl[((size_t)b * HWSZ + p0 + p) * CH + c0 + tx] = tile[tx][p];
    }
}

// ---------------- K1: offsets + bilinear sampling, float4 lanes ----------------
__global__ __launch_bounds__(128) void k_sample_cl(
    const float* __restrict__ xcl, const float* __restrict__ kp,
    const float* __restrict__ w1T, const float* __restrict__ b1,
    const float* __restrict__ w2,  const float* __restrict__ b2,
    float* __restrict__ feats)
{
    const int n  = blockIdx.x;        // 0..15999
    const int bi = n / NK;
    const int t  = threadIdx.x;       // 0..127

    __shared__ __align__(16) float patch[9 * CH];   // [pixel][channel]
    __shared__ float red[16 * 8];
    __shared__ float o1[16];
    __shared__ float offv[16];

    const float kx  = kp[(size_t)n * 2 + 0];
    const float ky  = kp[(size_t)n * 2 + 1];
    const float kwx = (kx * 0.5f + 0.5f) * (float)(WW - 1);
    const float kwy = (ky * 0.5f + 0.5f) * (float)(HH - 1);
    const int kwlx = (int)kwx;
    const int kwly = (int)kwy;
    int cx = (int)((float)kwlx - 0.5f);
    int cy = (int)((float)kwly - 0.5f);
    cx = min(max(cx, 0), WW - 1 - 3);
    cy = min(max(cy, 0), HH - 1 - 3);

    const float4* xb4 = (const float4*)(xcl + (size_t)bi * HWSZ * CH);  // [pix][32]

    // stage 3x3 patch: 288 float4 loads, 16B/lane
    #pragma unroll
    for (int i = 0; i < 3; ++i) {
        int idx = i * 128 + t;
        if (idx < 288) {
            int pix = idx >> 5, c4 = idx & 31;
            int py = cy + pix / 3, px = cx + pix % 3;
            ((float4*)patch)[idx] = xb4[((size_t)py * WW + px) * 32 + c4];
        }
    }
    __syncthreads();

    {
        const int o = t & 15, g = t >> 4;
        const float4* wp = (const float4*)(w1T + o * 1152 + g * 144);
        const float4* pp = (const float4*)(patch + g * 144);
        float s = 0.f;
        #pragma unroll
        for (int q = 0; q < 36; ++q) {
            float4 wv = wp[q];
            float4 pv = pp[q];
            s = fmaf(wv.x, pv.x, fmaf(wv.y, pv.y, fmaf(wv.z, pv.z, fmaf(wv.w, pv.w, s))));
        }
        red[o * 8 + g] = s;
    }
    __syncthreads();
    if (t < 16) {
        float s = b1[t];
        #pragma unroll
        for (int g = 0; g < 8; ++g) s += red[t * 8 + g];
        o1[t] = fmaxf(s, 0.f);
    }
    __syncthreads();
    if (t < 16) {
        float s = b2[t];
        #pragma unroll
        for (int j = 0; j < 16; ++j) s = fmaf(o1[j], w2[t * 16 + j], s);
        offv[t] = fminf(fmaxf(s, -80.f), 80.f);
    }
    __syncthreads();

    // sampling: group g = t>>5 handles positions g and g+4; lane32 = 4 channels
    const int gr = t >> 5, lane32 = t & 31;
    #pragma unroll
    for (int pp2 = 0; pp2 < 2; ++pp2) {
        const int p = gr + pp2 * 4;
        const float px = kwx + offv[p];
        const float py = kwy + offv[8 + p];
        const float x0 = floorf(px), y0 = floorf(py);
        const float wx = px - x0, wy = py - y0;
        float4 acc = {0.f, 0.f, 0.f, 0.f};
        #pragma unroll
        for (int dy = 0; dy < 2; ++dy) {
            const float yc = y0 + (float)dy;
            const bool vy = (yc >= 0.f) && (yc <= (float)(HH - 1));
            const int  yi = (int)fminf(fmaxf(yc, 0.f), (float)(HH - 1));
            const float wyv = dy ? wy : (1.f - wy);
            #pragma unroll
            for (int dx = 0; dx < 2; ++dx) {
                const float xc = x0 + (float)dx;
                const bool vx = (xc >= 0.f) && (xc <= (float)(WW - 1));
                const int  xi = (int)fminf(fmaxf(xc, 0.f), (float)(WW - 1));
                const float wgt = (vx && vy) ? (dx ? wx : (1.f - wx)) * wyv : 0.f;
                float4 v = xb4[((size_t)yi * WW + xi) * 32 + lane32];
                acc.x = fmaf(v.x, wgt, acc.x);
                acc.y = fmaf(v.y, wgt, acc.y);
                acc.z = fmaf(v.z, wgt, acc.z);
                acc.w = fmaf(v.w, wgt, acc.w);
            }
        }
        ((float4*)feats)[((size_t)n * 8 + p) * 32 + lane32] = acc;
    }
}

// ---------------- K2/K3a: MFMA bf16 GEMM, C[64 x 128] tile, K=128 per block --------
// A fp32 [m][apitch] (col offset kc*128), B bf16 fragment-packed, C fp32 [m][128].
// do_selu: apply selu epilogue. c_kc_stride: per-kc C offset (split-K partials).
__global__ __launch_bounds__(256) void k_gemm_mfma(
    const float* __restrict__ A, const unsigned short* __restrict__ B,
    float* __restrict__ C, int apitch, size_t c_kc_stride, int do_selu)
{
    const int m0 = blockIdx.x * 64;
    const int kc = blockIdx.y;
    const int t  = threadIdx.x;

    const float* Ab = A + (size_t)m0 * apitch + kc * 128;
    const unsigned short* Bb = B + (size_t)kc * 16384;
    float* Cb = C + (size_t)kc * c_kc_stride + (size_t)m0 * 128;

    __shared__ __align__(16) unsigned short Al[64 * 136];   // [m][k] bf16, +8 pad

    #pragma unroll
    for (int i = 0; i < 8; ++i) {
        int flat = i * 256 + t;
        int r = flat >> 5, c4 = flat & 31;
        float4 v = *(const float4*)(Ab + (size_t)r * apitch + c4 * 4);
        ushort4 o = {f2bf(v.x), f2bf(v.y), f2bf(v.z), f2bf(v.w)};
        *(ushort4*)(Al + r * 136 + c4 * 4) = o;
    }
    __syncthreads();

    const int w  = t >> 6, l = t & 63;
    const int fr = l & 15, fq = l >> 4;

    short8 a[4];
    #pragma unroll
    for (int q = 0; q < 4; ++q)
        a[q] = *(const short8*)(Al + (w * 16 + fr) * 136 + q * 32 + fq * 8);

    f32x4 acc[8];
    #pragma unroll
    for (int nt = 0; nt < 8; ++nt)
        #pragma unroll
        for (int r = 0; r < 4; ++r) acc[nt][r] = 0.f;

    #pragma unroll 2
    for (int nt = 0; nt < 8; ++nt) {
        short8 b[4];
        #pragma unroll
        for (int q = 0; q < 4; ++q)
            b[q] = *(const short8*)(Bb + ((size_t)(q * 8 + nt) * 64 + l) * 8);
        #pragma unroll
        for (int q = 0; q < 4; ++q)
            acc[nt] = __builtin_amdgcn_mfma_f32_16x16x32_bf16(a[q], b[q], acc[nt], 0, 0, 0);
    }

    #pragma unroll
    for (int nt = 0; nt < 8; ++nt) {
        #pragma unroll
        for (int r = 0; r < 4; ++r) {
            float v = acc[nt][r];
            if (do_selu) {
                float e = v > 0.f ? v : 1.6732632423543772f * expm1f(v);
                v = 1.0507009873554805f * e;
            }
            const int row = w * 16 + fq * 4 + r;
            const int col = nt * 16 + fr;
            Cb[(size_t)row * 128 + col] = v;
        }
    }
}

// ---------------- K3b: reduce 8 partials + L2 normalize ----------------
__global__ __launch_bounds__(256) void k_rn(const float* __restrict__ part,
                                            float* __restrict__ out)
{
    const int t = threadIdx.x;
    const int wv = t >> 6, l = t & 63;
    const int r = blockIdx.x * 4 + wv;
    float v0 = 0.f, v1 = 0.f;
    #pragma unroll
    for (int kc = 0; kc < 8; ++kc) {
        float2 v = *(const float2*)(part + ((size_t)kc * NKP + r) * 128 + 2 * l);
        v0 += v.x; v1 += v.y;
    }
    float s = v0 * v0 + v1 * v1;
    #pragma unroll
    for (int m = 32; m; m >>= 1) s += __shfl_xor(s, m);
    float inv = 1.f / fmaxf(sqrtf(s), 1e-12f);
    float2 o = {v0 * inv, v1 * inv};
    *(float2*)(out + (size_t)r * 128 + 2 * l) = o;
}

// ================= legacy fallback path (small ws) =================
__global__ __launch_bounds__(128) void k_sample(
    const float* __restrict__ x,  const float* __restrict__ kp,
    const float* __restrict__ w1, const float* __restrict__ b1,
    const float* __restrict__ w2, const float* __restrict__ b2,
    float* __restrict__ feats)
{
    const int n  = blockIdx.x;
    const int bi = n / NK;
    const int t  = threadIdx.x;

    __shared__ __align__(16) float patch[CH * 9];
    __shared__ float red[16 * 8];
    __shared__ float o1[16];
    __shared__ float offv[16];

    const float kx  = kp[(size_t)n * 2 + 0];
    const float ky  = kp[(size_t)n * 2 + 1];
    const float kwx = (kx * 0.5f + 0.5f) * (float)(WW - 1);
    const float kwy = (ky * 0.5f + 0.5f) * (float)(HH - 1);
    const int kwlx = (int)kwx;
    const int kwly = (int)kwy;
    int cx = (int)((float)kwlx - 0.5f);
    int cy = (int)((float)kwly - 0.5f);
    cx = min(max(cx, 0), WW - 1 - 3);
    cy = min(max(cy, 0), HH - 1 - 3);

    const float* xb = x + ((size_t)bi * CH + t) * HWSZ;
    {
        const float* p0 = xb + cy * WW + cx;
        #pragma unroll
        for (int i = 0; i < 3; ++i) {
            patch[t * 9 + i * 3 + 0] = p0[i * WW + 0];
            patch[t * 9 + i * 3 + 1] = p0[i * WW + 1];
            patch[t * 9 + i * 3 + 2] = p0[i * WW + 2];
        }
    }
    __syncthreads();
    {
        const int o = t & 15, g = t >> 4;
        const float4* wp = (const float4*)(w1 + o * 1152 + g * 144);
        const float4* pp = (const float4*)(patch + g * 144);
        float s = 0.f;
        #pragma unroll
        for (int q = 0; q < 36; ++q) {
            float4 wv = wp[q];
            float4 pv = pp[q];
            s = fmaf(wv.x, pv.x, fmaf(wv.y, pv.y, fmaf(wv.z, pv.z, fmaf(wv.w, pv.w, s))));
        }
        red[o * 8 + g] = s;
    }
    __syncthreads();
    if (t < 16) {
        float s = b1[t];
        #pragma unroll
        for (int g = 0; g < 8; ++g) s += red[t * 8 + g];
        o1[t] = fmaxf(s, 0.f);
    }
    __syncthreads();
    if (t < 16) {
        float s = b2[t];
        #pragma unroll
        for (int j = 0; j < 16; ++j) s = fmaf(o1[j], w2[t * 16 + j], s);
        offv[t] = fminf(fmaxf(s, -80.f), 80.f);
    }
    __syncthreads();

    #pragma unroll
    for (int p = 0; p < NPOS; ++p) {
        const float px = kwx + offv[p];
        const float py = kwy + offv[8 + p];
        const float x0 = floorf(px), y0 = floorf(py);
        const float wx = px - x0, wy = py - y0;
        float acc = 0.f;
        #pragma unroll
        for (int dy = 0; dy < 2; ++dy) {
            const float yc = y0 + (float)dy;
            const bool vy = (yc >= 0.f) && (yc <= (float)(HH - 1));
            const int  yi = (int)fminf(fmaxf(yc, 0.f), (float)(HH - 1));
            const float wyv = dy ? wy : (1.f - wy);
            #pragma unroll
            for (int dx = 0; dx < 2; ++dx) {
                const float xc = x0 + (float)dx;
                const bool vx = (xc >= 0.f) && (xc <= (float)(WW - 1));
                const int  xi = (int)fminf(fmaxf(xc, 0.f), (float)(WW - 1));
                const float wxv = dx ? wx : (1.f - wx);
                float v = xb[yi * WW + xi];
                v = (vx && vy) ? v : 0.f;
                acc = fmaf(v, wxv * wyv, acc);
            }
        }
        feats[((size_t)n * 8 + p) * CH + t] = acc;
    }
}

__global__ __launch_bounds__(256) void k_sf_legacy(float* __restrict__ gbuf,
                                                   const float* __restrict__ sfT)
{
    const int m0 = blockIdx.x * 64;
    const int t  = threadIdx.x;
    __shared__ __align__(16) float AT[128 * 68];

    #pragma unroll
    for (int i = 0; i < 32; ++i) {
        int flat = i * 256 + t;
        int mm = flat >> 7, kk = flat & 127;
        AT[kk * 68 + mm] = gbuf[(size_t)(m0 + mm) * 128 + kk];
    }
    __syncthreads();

    const int tx = t & 31, ty = t >> 5;
    const int d0 = tx * 4, mb = ty * 8;
    float acc[8][4];
    #pragma unroll
    for (int i = 0; i < 8; ++i)
        #pragma unroll
        for (int j = 0; j < 4; ++j) acc[i][j] = 0.f;

    #pragma unroll 4
    for (int k = 0; k < 128; ++k) {
        float4 a0 = *(const float4*)(AT + k * 68 + mb);
        float4 a1 = *(const float4*)(AT + k * 68 + mb + 4);
        float4 bq = *(const float4*)(sfT + k * 128 + d0);
        float a[8] = {a0.x, a0.y, a0.z, a0.w, a1.x, a1.y, a1.z, a1.w};
        float b4[4] = {bq.x, bq.y, bq.z, bq.w};
        #pragma unroll
        for (int i = 0; i < 8; ++i)
            #pragma unroll
            for (int j = 0; j < 4; ++j)
                acc[i][j] = fmaf(a[i], b4[j], acc[i][j]);
    }

    #pragma unroll
    for (int i = 0; i < 8; ++i) {
        float4 o;
        float* ov = &o.x;
        #pragma unroll
        for (int j = 0; j < 4; ++j) {
            float v = acc[i][j];
            float r = v > 0.f ? v : 1.6732632423543772f * expm1f(v);
            ov[j] = 1.0507009873554805f * r;
        }
        *(float4*)(gbuf + (size_t)(m0 + mb + i) * 128 + d0) = o;
    }
}

__global__ __launch_bounds__(256) void k_agg_mono(const float* __restrict__ gbuf,
                                                  const float* __restrict__ aggw,
                                                  float* __restrict__ out)
{
    const int m0 = blockIdx.x * 64;
    const int t  = threadIdx.x;
    __shared__ __align__(16) float AT[128 * 68];

    const int tx = t & 31, ty = t >> 5;
    const int d0 = tx * 4, mb = ty * 8;
    float acc[8][4];
    #pragma unroll
    for (int i = 0; i < 8; ++i)
        #pragma unroll
        for (int j = 0; j < 4; ++j) acc[i][j] = 0.f;

    for (int kc = 0; kc < 8; ++kc) {
        __syncthreads();
        #pragma unroll
        for (int i = 0; i < 32; ++i) {
            int flat = i * 256 + t;
            int mm = flat >> 7, kk = flat & 127;
            AT[kk * 68 + mm] = gbuf[(size_t)(m0 + mm) * 1024 + kc * 128 + kk];
        }
        __syncthreads();
        #pragma unroll 4
        for (int kk = 0; kk < 128; ++kk) {
            float4 a0 = *(const float4*)(AT + kk * 68 + mb);
            float4 a1 = *(const float4*)(AT + kk * 68 + mb + 4);
            float4 bq = *(const float4*)(aggw + (size_t)(kc * 128 + kk) * 128 + d0);
            float a[8] = {a0.x, a0.y, a0.z, a0.w, a1.x, a1.y, a1.z, a1.w};
            float b4[4] = {bq.x, bq.y, bq.z, bq.w};
            #pragma unroll
            for (int i = 0; i < 8; ++i)
                #pragma unroll
                for (int j = 0; j < 4; ++j)
                    acc[i][j] = fmaf(a[i], b4[j], acc[i][j]);
        }
    }

    #pragma unroll
    for (int i = 0; i < 8; ++i) {
        float s = acc[i][0] * acc[i][0] + acc[i][1] * acc[i][1]
                + acc[i][2] * acc[i][2] + acc[i][3] * acc[i][3];
        #pragma unroll
        for (int m = 16; m; m >>= 1) s += __shfl_xor(s, m);
        const float inv = 1.f / fmaxf(sqrtf(s), 1e-12f);
        float4 o = {acc[i][0] * inv, acc[i][1] * inv, acc[i][2] * inv, acc[i][3] * inv};
        *(float4*)(out + (size_t)(m0 + mb + i) * 128 + d0) = o;
    }
}

extern "C" void kernel_launch(void* const* d_in, const int* in_sizes, int n_in,
                              void* d_out, int out_size, void* d_ws, size_t ws_size,
                              hipStream_t stream)
{
    const float* x   = (const float*)d_in[0];
    const float* kp  = (const float*)d_in[1];
    const float* w1  = (const float*)d_in[2];
    const float* b1  = (const float*)d_in[3];
    const float* w2  = (const float*)d_in[4];
    const float* b2  = (const float*)d_in[5];
    const float* sfw = (const float*)d_in[6];
    const float* agg = (const float*)d_in[7];
    float* out = (float*)d_out;

    if (ws_size < WS_MIN) return;

    char*  ws    = (char*)d_ws;
    float* feats = (float*)ws;
    float* sfT   = (float*)(ws + OFF_SFT);
    float* w1T   = (float*)(ws + OFF_W1T);
    float* xcl   = (float*)(ws + OFF_XCL);              // reused as part[8][16000][128]
    unsigned short* sfB = (unsigned short*)(ws + OFF_SFB);
    unsigned short* agB = (unsigned short*)(ws + OFF_AGB);

    k_prep<<<712, 256, 0, stream>>>(sfw, w1, agg, sfT, w1T, sfB, agB);

    if (ws_size >= WS_FULL) {
        dim3 grid(HWSZ / 32, CH / 32, BB), blk(32, 8);
        k_tr       <<<grid, blk, 0, stream>>>(x, xcl);
        k_sample_cl<<<NKP, 128, 0, stream>>>(xcl, kp, w1T, b1, w2, b2, feats);
        k_gemm_mfma<<<dim3(2000, 1), 256, 0, stream>>>(feats, sfB, feats, 128, 0, 1);
        k_gemm_mfma<<<dim3(250, 8),  256, 0, stream>>>(feats, agB, xcl, 1024,
                                                       (size_t)NKP * 128, 0);
        k_rn       <<<4000, 256, 0, stream>>>(xcl, out);
    } else {
        k_sample   <<<NKP, 128, 0, stream>>>(x, kp, w1, b1, w2, b2, feats);
        k_sf_legacy<<<2000, 256, 0, stream>>>(feats, sfT);
        k_agg_mono <<<250,  256, 0, stream>>>(feats, agg, out);
    }
}

// Round 5
// 480.958 us; speedup vs baseline: 2.3163x; 1.0134x over previous
//
#include <hip/hip_runtime.h>
#include <cstdint>
#include <cmath>

#define BB   4
#define NK   4000
#define NKP  (BB*NK)      // 16000 keypoints total
#define CH   128
#define HH   240
#define WW   320
#define HWSZ (HH*WW)
#define NPOS 8

typedef __attribute__((ext_vector_type(8))) short short8;
typedef __attribute__((ext_vector_type(4))) float f32x4;

// ws layout (bytes):
//   feats_bf : 128000*128*2 = 32,768,000 @ 0
//   pos      : 16000*8*2*4  = 1,024,000  @ 32,768,000
//   sfT      : 65,536  @ 65,536,000  [legacy]
//   w1T      : 73,728  @ 65,601,536
//   xcl      : 157,286,400 @ 65,675,264   [NHWC x; dead after k_gather]
//     part   : 4*16000*128*4 = 32,768,000 @ 65,675,264   [aliases xcl]
//     g_bf   : 128000*128*2  = 32,768,000 @ 105,675,264  [aliases xcl tail]
//   sfB      : 32,768  @ 222,961,664  [bf16 MFMA-packed sf_w^T]
//   agB      : 262,144 @ 222,994,432  [bf16 MFMA-packed agg_w]
static constexpr size_t OFF_POS  = 32768000;
static constexpr size_t OFF_SFT  = 65536000;
static constexpr size_t OFF_W1T  = 65601536;
static constexpr size_t OFF_XCL  = 65675264;
static constexpr size_t OFF_G    = 105675264;
static constexpr size_t OFF_SFB  = 222961664;
static constexpr size_t OFF_AGB  = 222994432;
static constexpr size_t WS_FULL  = 223256576;
static constexpr size_t WS_MIN   = 65675264;

__device__ __forceinline__ unsigned short f2bf(float f) {   // RNE
    unsigned int u = __float_as_uint(f);
    u += 0x7fff + ((u >> 16) & 1);
    return (unsigned short)(u >> 16);
}

// ---------------- K0: weight prep ----------------
__global__ __launch_bounds__(256) void k_prep(const float* __restrict__ sfw,
                                              const float* __restrict__ w1,
                                              const float* __restrict__ aggw,
                                              float* __restrict__ sfT,
                                              float* __restrict__ w1T,
                                              unsigned short* __restrict__ sfB,
                                              unsigned short* __restrict__ agB)
{
    int id = blockIdx.x * 256 + threadIdx.x;   // 182272 total
    if (id < 16384) {
        int cc = id >> 7, dd = id & 127;
        sfT[cc * 128 + dd] = sfw[dd * 128 + cc];
    } else if (id < 16384 + 18432) {
        int j = id - 16384;
        int o = j / 1152, r = j % 1152;
        int k = r >> 7, c = r & 127;
        w1T[j] = w1[o * 1152 + c * 9 + k];
    } else if (id < 16384 + 18432 + 16384) {
        int idx = id - (16384 + 18432);
        int j = idx & 7, lane = (idx >> 3) & 63, nt = (idx >> 9) & 7, kc32 = (idx >> 12) & 3;
        int k = kc32 * 32 + (lane >> 4) * 8 + j;
        int n = nt * 16 + (lane & 15);
        sfB[idx] = f2bf(sfw[n * 128 + k]);     // B[c][d] = sf_w[d][c]
    } else if (id < 16384 + 18432 + 16384 + 131072) {
        int idx = id - (16384 + 18432 + 16384);
        int local = idx & 16383, kc = idx >> 14;
        int j = local & 7, lane = (local >> 3) & 63, nt = (local >> 9) & 7, kc32 = (local >> 12) & 3;
        int k = kc * 128 + kc32 * 32 + (lane >> 4) * 8 + j;
        int n = nt * 16 + (lane & 15);
        agB[idx] = f2bf(aggw[(size_t)k * 128 + n]);
    }
}

// ---------------- K0b: NCHW -> NHWC tiled transpose ----------------
__global__ __launch_bounds__(256) void k_tr(const float* __restrict__ x,
                                            float* __restrict__ xcl)
{
    const int b  = blockIdx.z;
    const int c0 = blockIdx.y * 32;
    const int p0 = blockIdx.x * 32;
    const int tx = threadIdx.x;
    const int ty = threadIdx.y;
    __shared__ float tile[32][33];

    #pragma unroll
    for (int i = 0; i < 4; ++i) {
        int c = ty + i * 8;
        tile[c][tx] = x[((size_t)(b * 128 + c0 + c)) * HWSZ + p0 + tx];
    }
    __syncthreads();
    #pragma unroll
    for (int i = 0; i < 4; ++i) {
        int p = ty + i * 8;
        xcl[((size_t)b * HWSZ + p0 + p) * CH + c0 + tx] = tile[tx][p];
    }
}

// ---------------- K1a: per-keypoint offset MLP -> sample positions ----------------
// block = 2 keypoints x 128 threads
__global__ __launch_bounds__(256) void k_offsets(
    const float* __restrict__ xcl, const float* __restrict__ kp,
    const float* __restrict__ w1T, const float* __restrict__ b1,
    const float* __restrict__ w2,  const float* __restrict__ b2,
    float* __restrict__ pos)
{
    const int which = threadIdx.x >> 7;
    const int t  = threadIdx.x & 127;
    const int n  = blockIdx.x * 2 + which;
    const int bi = n / NK;

    __shared__ __align__(16) float patch[2][9 * CH];
    __shared__ float red[2][16 * 8];
    __shared__ float o1[2][16];

    const float kx  = kp[(size_t)n * 2 + 0];
    const float ky  = kp[(size_t)n * 2 + 1];
    const float kwx = (kx * 0.5f + 0.5f) * (float)(WW - 1);
    const float kwy = (ky * 0.5f + 0.5f) * (float)(HH - 1);
    const int kwlx = (int)kwx;
    const int kwly = (int)kwy;
    int cx = (int)((float)kwlx - 0.5f);
    int cy = (int)((float)kwly - 0.5f);
    cx = min(max(cx, 0), WW - 1 - 3);
    cy = min(max(cy, 0), HH - 1 - 3);

    const float4* xb4 = (const float4*)(xcl + (size_t)bi * HWSZ * CH);

    #pragma unroll
    for (int i = 0; i < 3; ++i) {
        int idx = i * 128 + t;
        if (idx < 288) {
            int pix = idx >> 5, c4 = idx & 31;
            int py = cy + pix / 3, px = cx + pix % 3;
            ((float4*)patch[which])[idx] = xb4[((size_t)py * WW + px) * 32 + c4];
        }
    }
    __syncthreads();

    {
        const int o = t & 15, g = t >> 4;
        const float4* wp = (const float4*)(w1T + o * 1152 + g * 144);
        const float4* pp = (const float4*)(patch[which] + g * 144);
        float s = 0.f;
        #pragma unroll
        for (int q = 0; q < 36; ++q) {
            float4 wv = wp[q];
            float4 pv = pp[q];
            s = fmaf(wv.x, pv.x, fmaf(wv.y, pv.y, fmaf(wv.z, pv.z, fmaf(wv.w, pv.w, s))));
        }
        red[which][o * 8 + g] = s;
    }
    __syncthreads();
    if (t < 16) {
        float s = b1[t];
        #pragma unroll
        for (int g = 0; g < 8; ++g) s += red[which][t * 8 + g];
        o1[which][t] = fmaxf(s, 0.f);
    }
    __syncthreads();
    if (t < 8) {
        float sx = b2[t], sy = b2[8 + t];
        #pragma unroll
        for (int j = 0; j < 16; ++j) {
            float o1v = o1[which][j];
            sx = fmaf(o1v, w2[t * 16 + j], sx);
            sy = fmaf(o1v, w2[(8 + t) * 16 + j], sy);
        }
        sx = fminf(fmaxf(sx, -80.f), 80.f);
        sy = fminf(fmaxf(sy, -80.f), 80.f);
        float2 o = {kwx + sx, kwy + sy};
        ((float2*)pos)[(size_t)n * 8 + t] = o;
    }
}

// ---------------- K1b: bilinear gather, barrier-free, bf16 out ----------------
// wave = 2 samples x 32 f4-lanes; block = 8 sample slots x 4 iterations = 32 samples
__global__ __launch_bounds__(256) void k_gather(
    const float* __restrict__ xcl, const float* __restrict__ pos,
    unsigned short* __restrict__ fb)
{
    const int t = threadIdx.x;
    const int lane32 = t & 31;
    const int slot   = t >> 5;          // 0..7
    const int base   = blockIdx.x * 32;

    #pragma unroll
    for (int it = 0; it < 4; ++it) {
        const int s = base + it * 8 + slot;      // sample id 0..127999
        float2 P = ((const float2*)pos)[s];
        const int bi = s / (NK * NPOS);
        const float4* xb4 = (const float4*)xcl + (size_t)bi * HWSZ * 32;

        const float x0 = floorf(P.x), y0 = floorf(P.y);
        const float wx = P.x - x0, wy = P.y - y0;
        float4 acc = {0.f, 0.f, 0.f, 0.f};
        #pragma unroll
        for (int dy = 0; dy < 2; ++dy) {
            const float yc = y0 + (float)dy;
            const bool vy = (yc >= 0.f) && (yc <= (float)(HH - 1));
            const int  yi = (int)fminf(fmaxf(yc, 0.f), (float)(HH - 1));
            const float wyv = dy ? wy : (1.f - wy);
            #pragma unroll
            for (int dx = 0; dx < 2; ++dx) {
                const float xc = x0 + (float)dx;
                const bool vx = (xc >= 0.f) && (xc <= (float)(WW - 1));
                const int  xi = (int)fminf(fmaxf(xc, 0.f), (float)(WW - 1));
                const float wgt = (vx && vy) ? (dx ? wx : (1.f - wx)) * wyv : 0.f;
                float4 v = xb4[((size_t)yi * WW + xi) * 32 + lane32];
                acc.x = fmaf(v.x, wgt, acc.x);
                acc.y = fmaf(v.y, wgt, acc.y);
                acc.z = fmaf(v.z, wgt, acc.z);
                acc.w = fmaf(v.w, wgt, acc.w);
            }
        }
        ushort4 o = {f2bf(acc.x), f2bf(acc.y), f2bf(acc.z), f2bf(acc.w)};
        *(ushort4*)(fb + (size_t)s * 128 + lane32 * 4) = o;
    }
}

// ---------------- K2: g = selu(feats @ sf_w^T), bf16 in/out, MFMA ----------------
__global__ __launch_bounds__(256) void k_sf_mfma(
    const unsigned short* __restrict__ fb, const unsigned short* __restrict__ sfB,
    unsigned short* __restrict__ g)
{
    const int m0 = blockIdx.x * 64;
    const int t  = threadIdx.x;
    __shared__ __align__(16) unsigned short Al[64 * 136];

    #pragma unroll
    for (int i = 0; i < 4; ++i) {
        int flat = i * 256 + t;
        int r = flat >> 4, c8 = flat & 15;
        *(short8*)(Al + r * 136 + c8 * 8) =
            *(const short8*)(fb + (size_t)(m0 + r) * 128 + c8 * 8);
    }
    __syncthreads();

    const int w = t >> 6, l = t & 63;
    const int fr = l & 15, fq = l >> 4;

    short8 a[4];
    #pragma unroll
    for (int q = 0; q < 4; ++q)
        a[q] = *(const short8*)(Al + (w * 16 + fr) * 136 + q * 32 + fq * 8);

    f32x4 acc[8];
    #pragma unroll
    for (int nt = 0; nt < 8; ++nt)
        #pragma unroll
        for (int r = 0; r < 4; ++r) acc[nt][r] = 0.f;

    #pragma unroll 2
    for (int nt = 0; nt < 8; ++nt) {
        short8 b[4];
        #pragma unroll
        for (int q = 0; q < 4; ++q)
            b[q] = *(const short8*)(sfB + ((size_t)(q * 8 + nt) * 64 + l) * 8);
        #pragma unroll
        for (int q = 0; q < 4; ++q)
            acc[nt] = __builtin_amdgcn_mfma_f32_16x16x32_bf16(a[q], b[q], acc[nt], 0, 0, 0);
    }

    // selu + bf16, transposed through LDS for coalesced 16B stores
    __syncthreads();
    #pragma unroll
    for (int nt = 0; nt < 8; ++nt)
        #pragma unroll
        for (int r = 0; r < 4; ++r) {
            float v = acc[nt][r];
            float e = v > 0.f ? v : 1.6732632423543772f * expm1f(v);
            Al[(w * 16 + fq * 4 + r) * 136 + nt * 16 + fr] = f2bf(1.0507009873554805f * e);
        }
    __syncthreads();
    #pragma unroll
    for (int i = 0; i < 4; ++i) {
        int flat = i * 256 + t;
        int r = flat >> 4, c8 = flat & 15;
        *(short8*)(g + (size_t)(m0 + r) * 128 + c8 * 8) =
            *(const short8*)(Al + r * 136 + c8 * 8);
    }
}

// ---------------- K3a: split-K (4 chunks of 256) agg GEMM, bf16 A, fp32 partials ---
__global__ __launch_bounds__(256) void k_agg_mfma(
    const unsigned short* __restrict__ g, const unsigned short* __restrict__ agB,
    float* __restrict__ part)
{
    const int m0 = blockIdx.x * 64;     // 250 m-tiles (keypoint rows)
    const int kb = blockIdx.y;          // 0..3
    const int t  = threadIdx.x;
    __shared__ __align__(16) unsigned short Al[64 * 136];

    const int w = t >> 6, l = t & 63;
    const int fr = l & 15, fq = l >> 4;

    f32x4 acc[8];
    #pragma unroll
    for (int nt = 0; nt < 8; ++nt)
        #pragma unroll
        for (int r = 0; r < 4; ++r) acc[nt][r] = 0.f;

    #pragma unroll
    for (int h = 0; h < 2; ++h) {
        const int kc = kb * 2 + h;
        if (h) __syncthreads();
        #pragma unroll
        for (int i = 0; i < 4; ++i) {
            int flat = i * 256 + t;
            int r = flat >> 4, c8 = flat & 15;
            *(short8*)(Al + r * 136 + c8 * 8) =
                *(const short8*)(g + (size_t)(m0 + r) * 1024 + kc * 128 + c8 * 8);
        }
        __syncthreads();

        short8 a[4];
        #pragma unroll
        for (int q = 0; q < 4; ++q)
            a[q] = *(const short8*)(Al + (w * 16 + fr) * 136 + q * 32 + fq * 8);

        const unsigned short* Bb = agB + (size_t)kc * 16384;
        #pragma unroll 2
        for (int nt = 0; nt < 8; ++nt) {
            short8 b[4];
            #pragma unroll
            for (int q = 0; q < 4; ++q)
                b[q] = *(const short8*)(Bb + ((size_t)(q * 8 + nt) * 64 + l) * 8);
            #pragma unroll
            for (int q = 0; q < 4; ++q)
                acc[nt] = __builtin_amdgcn_mfma_f32_16x16x32_bf16(a[q], b[q], acc[nt], 0, 0, 0);
        }
    }

    float* Cb = part + (size_t)kb * NKP * 128 + (size_t)m0 * 128;
    #pragma unroll
    for (int nt = 0; nt < 8; ++nt)
        #pragma unroll
        for (int r = 0; r < 4; ++r)
            Cb[(size_t)(w * 16 + fq * 4 + r) * 128 + nt * 16 + fr] = acc[nt][r];
}

// ---------------- K3b: reduce 4 partials + L2 normalize ----------------
__global__ __launch_bounds__(256) void k_rn(const float* __restrict__ part,
                                            float* __restrict__ out)
{
    const int t = threadIdx.x;
    const int wv = t >> 6, l = t & 63;
    const int r = blockIdx.x * 4 + wv;
    float v0 = 0.f, v1 = 0.f;
    #pragma unroll
    for (int kc = 0; kc < 4; ++kc) {
        float2 v = *(const float2*)(part + ((size_t)kc * NKP + r) * 128 + 2 * l);
        v0 += v.x; v1 += v.y;
    }
    float s = v0 * v0 + v1 * v1;
    #pragma unroll
    for (int m = 32; m; m >>= 1) s += __shfl_xor(s, m);
    float inv = 1.f / fmaxf(sqrtf(s), 1e-12f);
    float2 o = {v0 * inv, v1 * inv};
    *(float2*)(out + (size_t)r * 128 + 2 * l) = o;
}

// ================= legacy fallback path (small ws) =================
__global__ __launch_bounds__(128) void k_sample(
    const float* __restrict__ x,  const float* __restrict__ kp,
    const float* __restrict__ w1, const float* __restrict__ b1,
    const float* __restrict__ w2, const float* __restrict__ b2,
    float* __restrict__ feats)
{
    const int n  = blockIdx.x;
    const int bi = n / NK;
    const int t  = threadIdx.x;

    __shared__ __align__(16) float patch[CH * 9];
    __shared__ float red[16 * 8];
    __shared__ float o1[16];
    __shared__ float offv[16];

    const float kx  = kp[(size_t)n * 2 + 0];
    const float ky  = kp[(size_t)n * 2 + 1];
    const float kwx = (kx * 0.5f + 0.5f) * (float)(WW - 1);
    const float kwy = (ky * 0.5f + 0.5f) * (float)(HH - 1);
    const int kwlx = (int)kwx;
    const int kwly = (int)kwy;
    int cx = (int)((float)kwlx - 0.5f);
    int cy = (int)((float)kwly - 0.5f);
    cx = min(max(cx, 0), WW - 1 - 3);
    cy = min(max(cy, 0), HH - 1 - 3);

    const float* xb = x + ((size_t)bi * CH + t) * HWSZ;
    {
        const float* p0 = xb + cy * WW + cx;
        #pragma unroll
        for (int i = 0; i < 3; ++i) {
            patch[t * 9 + i * 3 + 0] = p0[i * WW + 0];
            patch[t * 9 + i * 3 + 1] = p0[i * WW + 1];
            patch[t * 9 + i * 3 + 2] = p0[i * WW + 2];
        }
    }
    __syncthreads();
    {
        const int o = t & 15, g = t >> 4;
        const float4* wp = (const float4*)(w1 + o * 1152 + g * 144);
        const float4* pp = (const float4*)(patch + g * 144);
        float s = 0.f;
        #pragma unroll
        for (int q = 0; q < 36; ++q) {
            float4 wv = wp[q];
            float4 pv = pp[q];
            s = fmaf(wv.x, pv.x, fmaf(wv.y, pv.y, fmaf(wv.z, pv.z, fmaf(wv.w, pv.w, s))));
        }
        red[o * 8 + g] = s;
    }
    __syncthreads();
    if (t < 16) {
        float s = b1[t];
        #pragma unroll
        for (int g = 0; g < 8; ++g) s += red[t * 8 + g];
        o1[t] = fmaxf(s, 0.f);
    }
    __syncthreads();
    if (t < 16) {
        float s = b2[t];
        #pragma unroll
        for (int j = 0; j < 16; ++j) s = fmaf(o1[j], w2[t * 16 + j], s);
        offv[t] = fminf(fmaxf(s, -80.f), 80.f);
    }
    __syncthreads();

    #pragma unroll
    for (int p = 0; p < NPOS; ++p) {
        const float px = kwx + offv[p];
        const float py = kwy + offv[8 + p];
        const float x0 = floorf(px), y0 = floorf(py);
        const float wx = px - x0, wy = py - y0;
        float acc = 0.f;
        #pragma unroll
        for (int dy = 0; dy < 2; ++dy) {
            const float yc = y0 + (float)dy;
            const bool vy = (yc >= 0.f) && (yc <= (float)(HH - 1));
            const int  yi = (int)fminf(fmaxf(yc, 0.f), (float)(HH - 1));
            const float wyv = dy ? wy : (1.f - wy);
            #pragma unroll
            for (int dx = 0; dx < 2; ++dx) {
                const float xc = x0 + (float)dx;
                const bool vx = (xc >= 0.f) && (xc <= (float)(WW - 1));
                const int  xi = (int)fminf(fmaxf(xc, 0.f), (float)(WW - 1));
                const float wxv = dx ? wx : (1.f - wx);
                float v = xb[yi * WW + xi];
                v = (vx && vy) ? v : 0.f;
                acc = fmaf(v, wxv * wyv, acc);
            }
        }
        feats[((size_t)n * 8 + p) * CH + t] = acc;
    }
}

__global__ __launch_bounds__(256) void k_sf_legacy(float* __restrict__ gbuf,
                                                   const float* __restrict__ sfT)
{
    const int m0 = blockIdx.x * 64;
    const int t  = threadIdx.x;
    __shared__ __align__(16) float AT[128 * 68];

    #pragma unroll
    for (int i = 0; i < 32; ++i) {
        int flat = i * 256 + t;
        int mm = flat >> 7, kk = flat & 127;
        AT[kk * 68 + mm] = gbuf[(size_t)(m0 + mm) * 128 + kk];
    }
    __syncthreads();

    const int tx = t & 31, ty = t >> 5;
    const int d0 = tx * 4, mb = ty * 8;
    float acc[8][4];
    #pragma unroll
    for (int i = 0; i < 8; ++i)
        #pragma unroll
        for (int j = 0; j < 4; ++j) acc[i][j] = 0.f;

    #pragma unroll 4
    for (int k = 0; k < 128; ++k) {
        float4 a0 = *(const float4*)(AT + k * 68 + mb);
        float4 a1 = *(const float4*)(AT + k * 68 + mb + 4);
        float4 bq = *(const float4*)(sfT + k * 128 + d0);
        float a[8] = {a0.x, a0.y, a0.z, a0.w, a1.x, a1.y, a1.z, a1.w};
        float b4[4] = {bq.x, bq.y, bq.z, bq.w};
        #pragma unroll
        for (int i = 0; i < 8; ++i)
            #pragma unroll
            for (int j = 0; j < 4; ++j)
                acc[i][j] = fmaf(a[i], b4[j], acc[i][j]);
    }

    #pragma unroll
    for (int i = 0; i < 8; ++i) {
        float4 o;
        float* ov = &o.x;
        #pragma unroll
        for (int j = 0; j < 4; ++j) {
            float v = acc[i][j];
            float r = v > 0.f ? v : 1.6732632423543772f * expm1f(v);
            ov[j] = 1.0507009873554805f * r;
        }
        *(float4*)(gbuf + (size_t)(m0 + mb + i) * 128 + d0) = o;
    }
}

__global__ __launch_bounds__(256) void k_agg_mono(const float* __restrict__ gbuf,
                                                  const float* __restrict__ aggw,
                                                  float* __restrict__ out)
{
    const int m0 = blockIdx.x * 64;
    const int t  = threadIdx.x;
    __shared__ __align__(16) float AT[128 * 68];

    const int tx = t & 31, ty = t >> 5;
    const int d0 = tx * 4, mb = ty * 8;
    float acc[8][4];
    #pragma unroll
    for (int i = 0; i < 8; ++i)
        #pragma unroll
        for (int j = 0; j < 4; ++j) acc[i][j] = 0.f;

    for (int kc = 0; kc < 8; ++kc) {
        __syncthreads();
        #pragma unroll
        for (int i = 0; i < 32; ++i) {
            int flat = i * 256 + t;
            int mm = flat >> 7, kk = flat & 127;
            AT[kk * 68 + mm] = gbuf[(size_t)(m0 + mm) * 1024 + kc * 128 + kk];
        }
        __syncthreads();
        #pragma unroll 4
        for (int kk = 0; kk < 128; ++kk) {
            float4 a0 = *(const float4*)(AT + kk * 68 + mb);
            float4 a1 = *(const float4*)(AT + kk * 68 + mb + 4);
            float4 bq = *(const float4*)(aggw + (size_t)(kc * 128 + kk) * 128 + d0);
            float a[8] = {a0.x, a0.y, a0.z, a0.w, a1.x, a1.y, a1.z, a1.w};
            float b4[4] = {bq.x, bq.y, bq.z, bq.w};
            #pragma unroll
            for (int i = 0; i < 8; ++i)
                #pragma unroll
                for (int j = 0; j < 4; ++j)
                    acc[i][j] = fmaf(a[i], b4[j], acc[i][j]);
        }
    }

    #pragma unroll
    for (int i = 0; i < 8; ++i) {
        float s = acc[i][0] * acc[i][0] + acc[i][1] * acc[i][1]
                + acc[i][2] * acc[i][2] + acc[i][3] * acc[i][3];
        #pragma unroll
        for (int m = 16; m; m >>= 1) s += __shfl_xor(s, m);
        const float inv = 1.f / fmaxf(sqrtf(s), 1e-12f);
        float4 o = {acc[i][0] * inv, acc[i][1] * inv, acc[i][2] * inv, acc[i][3] * inv};
        *(float4*)(out + (size_t)(m0 + mb + i) * 128 + d0) = o;
    }
}

extern "C" void kernel_launch(void* const* d_in, const int* in_sizes, int n_in,
                              void* d_out, int out_size, void* d_ws, size_t ws_size,
                              hipStream_t stream)
{
    const float* x   = (const float*)d_in[0];
    const float* kp  = (const float*)d_in[1];
    const float* w1  = (const float*)d_in[2];
    const float* b1  = (const float*)d_in[3];
    const float* w2  = (const float*)d_in[4];
    const float* b2  = (const float*)d_in[5];
    const float* sfw = (const float*)d_in[6];
    const float* agg = (const float*)d_in[7];
    float* out = (float*)d_out;

    if (ws_size < WS_MIN) return;

    char*  ws    = (char*)d_ws;
    unsigned short* fb = (unsigned short*)ws;           // feats bf16 [128000][128]
    float* pos   = (float*)(ws + OFF_POS);              // [16000][8][2]
    float* sfT   = (float*)(ws + OFF_SFT);
    float* w1T   = (float*)(ws + OFF_W1T);
    float* xcl   = (float*)(ws + OFF_XCL);              // NHWC x
    float* part  = (float*)(ws + OFF_XCL);              // aliases xcl (dead after gather)
    unsigned short* g   = (unsigned short*)(ws + OFF_G);  // aliases xcl tail
    unsigned short* sfB = (unsigned short*)(ws + OFF_SFB);
    unsigned short* agB = (unsigned short*)(ws + OFF_AGB);

    k_prep<<<712, 256, 0, stream>>>(sfw, w1, agg, sfT, w1T, sfB, agB);

    if (ws_size >= WS_FULL) {
        dim3 grid(HWSZ / 32, CH / 32, BB), blk(32, 8);
        k_tr      <<<grid, blk, 0, stream>>>(x, xcl);
        k_offsets <<<NKP / 2, 256, 0, stream>>>(xcl, kp, w1T, b1, w2, b2, pos);
        k_gather  <<<4000, 256, 0, stream>>>(xcl, pos, fb);
        k_sf_mfma <<<2000, 256, 0, stream>>>(fb, sfB, g);
        k_agg_mfma<<<dim3(250, 4), 256, 0, stream>>>(g, agB, part);
        k_rn      <<<4000, 256, 0, stream>>>(part, out);
    } else {
        float* feats = (float*)ws;
        k_sample   <<<NKP, 128, 0, stream>>>(x, kp, w1, b1, w2, b2, feats);
        k_sf_legacy<<<2000, 256, 0, stream>>>(feats, sfT);
        k_agg_mono <<<250,  256, 0, stream>>>(feats, agg, out);
    }
}

// Round 6
// 380.897 us; speedup vs baseline: 2.9248x; 1.2627x over previous
//
#include <hip/hip_runtime.h>
#include <cstdint>
#include <cmath>

#define BB   4
#define NK   4000
#define NKP  (BB*NK)      // 16000 keypoints total
#define CH   128
#define HH   240
#define WW   320
#define HWSZ (HH*WW)
#define NPOS 8

typedef __attribute__((ext_vector_type(8))) short short8;
typedef __attribute__((ext_vector_type(4))) float f32x4;

// ws layout (bytes):
//   feats_bf : 128000*128*2 = 32,768,000 @ 0
//   pos      : 16000*8*2*4  = 1,024,000  @ 32,768,000
//   sfT      : 65,536  @ 65,536,000  [legacy]
//   w1T      : 73,728  @ 65,601,536
//   xcl      : 157,286,400 @ 65,675,264   [NHWC x; dead after k_gather]
//     part   : 4*16000*128*4 = 32,768,000 @ 65,675,264   [aliases xcl]
//     g_bf   : 128000*128*2  = 32,768,000 @ 105,675,264  [aliases xcl tail]
//   sfB      : 32,768  @ 222,961,664  [bf16 MFMA-packed sf_w^T]
//   agB      : 262,144 @ 222,994,432  [bf16 MFMA-packed agg_w]
static constexpr size_t OFF_POS  = 32768000;
static constexpr size_t OFF_SFT  = 65536000;
static constexpr size_t OFF_W1T  = 65601536;
static constexpr size_t OFF_XCL  = 65675264;
static constexpr size_t OFF_G    = 105675264;
static constexpr size_t OFF_SFB  = 222961664;
static constexpr size_t OFF_AGB  = 222994432;
static constexpr size_t WS_FULL  = 223256576;
static constexpr size_t WS_MIN   = 65675264;

__device__ __forceinline__ unsigned short f2bf(float f) {   // RNE
    unsigned int u = __float_as_uint(f);
    u += 0x7fff + ((u >> 16) & 1);
    return (unsigned short)(u >> 16);
}

// ---------------- K0: weight prep ----------------
__global__ __launch_bounds__(256) void k_prep(const float* __restrict__ sfw,
                                              const float* __restrict__ w1,
                                              const float* __restrict__ aggw,
                                              float* __restrict__ sfT,
                                              float* __restrict__ w1T,
                                              unsigned short* __restrict__ sfB,
                                              unsigned short* __restrict__ agB)
{
    int id = blockIdx.x * 256 + threadIdx.x;   // 182272 total
    if (id < 16384) {
        int cc = id >> 7, dd = id & 127;
        sfT[cc * 128 + dd] = sfw[dd * 128 + cc];
    } else if (id < 16384 + 18432) {
        int j = id - 16384;
        int o = j / 1152, r = j % 1152;
        int k = r >> 7, c = r & 127;
        w1T[j] = w1[o * 1152 + c * 9 + k];
    } else if (id < 16384 + 18432 + 16384) {
        int idx = id - (16384 + 18432);
        int j = idx & 7, lane = (idx >> 3) & 63, nt = (idx >> 9) & 7, kc32 = (idx >> 12) & 3;
        int k = kc32 * 32 + (lane >> 4) * 8 + j;
        int n = nt * 16 + (lane & 15);
        sfB[idx] = f2bf(sfw[n * 128 + k]);     // B[c][d] = sf_w[d][c]
    } else if (id < 16384 + 18432 + 16384 + 131072) {
        int idx = id - (16384 + 18432 + 16384);
        int local = idx & 16383, kc = idx >> 14;
        int j = local & 7, lane = (local >> 3) & 63, nt = (local >> 9) & 7, kc32 = (local >> 12) & 3;
        int k = kc * 128 + kc32 * 32 + (lane >> 4) * 8 + j;
        int n = nt * 16 + (lane & 15);
        agB[idx] = f2bf(aggw[(size_t)k * 128 + n]);
    }
}

// ---------------- K0b: NCHW -> NHWC tiled transpose ----------------
__global__ __launch_bounds__(256) void k_tr(const float* __restrict__ x,
                                            float* __restrict__ xcl)
{
    const int b  = blockIdx.z;
    const int c0 = blockIdx.y * 32;
    const int p0 = blockIdx.x * 32;
    const int tx = threadIdx.x;
    const int ty = threadIdx.y;
    __shared__ float tile[32][33];

    #pragma unroll
    for (int i = 0; i < 4; ++i) {
        int c = ty + i * 8;
        tile[c][tx] = x[((size_t)(b * 128 + c0 + c)) * HWSZ + p0 + tx];
    }
    __syncthreads();
    #pragma unroll
    for (int i = 0; i < 4; ++i) {
        int p = ty + i * 8;
        xcl[((size_t)b * HWSZ + p0 + p) * CH + c0 + tx] = tile[tx][p];
    }
}

// ---------------- K1a: offset conv+MLP, 16 kp/block, weights LDS-resident ---------
// LDS ~51 KB: per K-chunk (one patch row, 384 floats) stage w1T[16][384] and
// patches[16][384] fp32, conv with thread=(o=t>>4, kp=t&15); weight reads are
// 16-lane broadcasts (388-pad -> conflict-free), patch reads 2-way (free).
__global__ __launch_bounds__(256) void k_offsets2(
    const float* __restrict__ xcl, const float* __restrict__ kp,
    const float* __restrict__ w1T, const float* __restrict__ b1,
    const float* __restrict__ w2,  const float* __restrict__ b2,
    float* __restrict__ pos)
{
    const int t  = threadIdx.x;
    const int n0 = blockIdx.x * 16;

    __shared__ __align__(16) float wl[16 * 388];
    __shared__ __align__(16) float pl[16 * 388];
    __shared__ float o1l[16 * 16];
    __shared__ float kwl[16 * 2];

    if (t < 16) {
        const int n = n0 + t;
        float kx = kp[2 * n], ky = kp[2 * n + 1];
        kwl[t * 2 + 0] = (kx * 0.5f + 0.5f) * (float)(WW - 1);
        kwl[t * 2 + 1] = (ky * 0.5f + 0.5f) * (float)(HH - 1);
    }

    const int o_c  = t >> 4;
    const int kp_c = t & 15;

    float acc0 = 0.f, acc1 = 0.f;

    for (int h = 0; h < 3; ++h) {
        if (h) __syncthreads();
        // stage weight chunk: 16 o x 96 f4
        #pragma unroll
        for (int i = 0; i < 6; ++i) {
            int idx = i * 256 + t;
            int o = idx / 96, c4 = idx % 96;
            *(float4*)&wl[o * 388 + c4 * 4] =
                *(const float4*)&w1T[o * 1152 + h * 384 + c4 * 4];
        }
        // stage patch chunk (patch row h): 16 kp x 96 f4
        #pragma unroll
        for (int i = 0; i < 6; ++i) {
            int idx = i * 256 + t;
            int kk = idx / 96, r = idx % 96;
            int px = r >> 5, c4 = r & 31;
            int n = n0 + kk;
            int bi = n / NK;
            float kx = kp[2 * n], ky = kp[2 * n + 1];
            float kwx = (kx * 0.5f + 0.5f) * (float)(WW - 1);
            float kwy = (ky * 0.5f + 0.5f) * (float)(HH - 1);
            int cx = (int)((float)((int)kwx) - 0.5f);
            int cy = (int)((float)((int)kwy) - 0.5f);
            cx = min(max(cx, 0), WW - 4);
            cy = min(max(cy, 0), HH - 4);
            const float4* xb4 = (const float4*)xcl + (size_t)bi * HWSZ * 32;
            *(float4*)&pl[kk * 388 + r * 4] =
                xb4[((size_t)(cy + h) * WW + (cx + px)) * 32 + c4];
        }
        __syncthreads();
        #pragma unroll 4
        for (int q = 0; q < 96; q += 2) {
            float4 w0 = *(const float4*)&wl[o_c * 388 + q * 4];
            float4 p0 = *(const float4*)&pl[kp_c * 388 + q * 4];
            float4 w1v = *(const float4*)&wl[o_c * 388 + q * 4 + 4];
            float4 p1 = *(const float4*)&pl[kp_c * 388 + q * 4 + 4];
            acc0 = fmaf(w0.x, p0.x, fmaf(w0.y, p0.y, fmaf(w0.z, p0.z, fmaf(w0.w, p0.w, acc0))));
            acc1 = fmaf(w1v.x, p1.x, fmaf(w1v.y, p1.y, fmaf(w1v.z, p1.z, fmaf(w1v.w, p1.w, acc1))));
        }
    }

    o1l[kp_c * 16 + o_c] = fmaxf(acc0 + acc1 + b1[o_c], 0.f);
    __syncthreads();

    if (t < 128) {
        const int kk = t >> 3, j = t & 7;
        float sx = b2[j], sy = b2[8 + j];
        #pragma unroll
        for (int i = 0; i < 16; ++i) {
            float v = o1l[kk * 16 + i];
            sx = fmaf(v, w2[j * 16 + i], sx);
            sy = fmaf(v, w2[(8 + j) * 16 + i], sy);
        }
        sx = fminf(fmaxf(sx, -80.f), 80.f);
        sy = fminf(fmaxf(sy, -80.f), 80.f);
        float2 o = {kwl[kk * 2 + 0] + sx, kwl[kk * 2 + 1] + sy};
        ((float2*)pos)[(size_t)(n0 + kk) * 8 + j] = o;
    }
}

// ---------------- K1b: bilinear gather, barrier-free, bf16 out ----------------
__global__ __launch_bounds__(256) void k_gather(
    const float* __restrict__ xcl, const float* __restrict__ pos,
    unsigned short* __restrict__ fb)
{
    const int t = threadIdx.x;
    const int lane32 = t & 31;
    const int slot   = t >> 5;          // 0..7
    const int base   = blockIdx.x * 32;

    #pragma unroll
    for (int it = 0; it < 4; ++it) {
        const int s = base + it * 8 + slot;      // sample id 0..127999
        float2 P = ((const float2*)pos)[s];
        const int bi = s / (NK * NPOS);
        const float4* xb4 = (const float4*)xcl + (size_t)bi * HWSZ * 32;

        const float x0 = floorf(P.x), y0 = floorf(P.y);
        const float wx = P.x - x0, wy = P.y - y0;
        float4 acc = {0.f, 0.f, 0.f, 0.f};
        #pragma unroll
        for (int dy = 0; dy < 2; ++dy) {
            const float yc = y0 + (float)dy;
            const bool vy = (yc >= 0.f) && (yc <= (float)(HH - 1));
            const int  yi = (int)fminf(fmaxf(yc, 0.f), (float)(HH - 1));
            const float wyv = dy ? wy : (1.f - wy);
            #pragma unroll
            for (int dx = 0; dx < 2; ++dx) {
                const float xc = x0 + (float)dx;
                const bool vx = (xc >= 0.f) && (xc <= (float)(WW - 1));
                const int  xi = (int)fminf(fmaxf(xc, 0.f), (float)(WW - 1));
                const float wgt = (vx && vy) ? (dx ? wx : (1.f - wx)) * wyv : 0.f;
                float4 v = xb4[((size_t)yi * WW + xi) * 32 + lane32];
                acc.x = fmaf(v.x, wgt, acc.x);
                acc.y = fmaf(v.y, wgt, acc.y);
                acc.z = fmaf(v.z, wgt, acc.z);
                acc.w = fmaf(v.w, wgt, acc.w);
            }
        }
        ushort4 o = {f2bf(acc.x), f2bf(acc.y), f2bf(acc.z), f2bf(acc.w)};
        *(ushort4*)(fb + (size_t)s * 128 + lane32 * 4) = o;
    }
}

// ---------------- K2: g = selu(feats @ sf_w^T), bf16 in/out, MFMA ----------------
__global__ __launch_bounds__(256) void k_sf_mfma(
    const unsigned short* __restrict__ fb, const unsigned short* __restrict__ sfB,
    unsigned short* __restrict__ g)
{
    const int m0 = blockIdx.x * 64;
    const int t  = threadIdx.x;
    __shared__ __align__(16) unsigned short Al[64 * 136];

    #pragma unroll
    for (int i = 0; i < 4; ++i) {
        int flat = i * 256 + t;
        int r = flat >> 4, c8 = flat & 15;
        *(short8*)(Al + r * 136 + c8 * 8) =
            *(const short8*)(fb + (size_t)(m0 + r) * 128 + c8 * 8);
    }
    __syncthreads();

    const int w = t >> 6, l = t & 63;
    const int fr = l & 15, fq = l >> 4;

    short8 a[4];
    #pragma unroll
    for (int q = 0; q < 4; ++q)
        a[q] = *(const short8*)(Al + (w * 16 + fr) * 136 + q * 32 + fq * 8);

    f32x4 acc[8];
    #pragma unroll
    for (int nt = 0; nt < 8; ++nt)
        #pragma unroll
        for (int r = 0; r < 4; ++r) acc[nt][r] = 0.f;

    #pragma unroll 2
    for (int nt = 0; nt < 8; ++nt) {
        short8 b[4];
        #pragma unroll
        for (int q = 0; q < 4; ++q)
            b[q] = *(const short8*)(sfB + ((size_t)(q * 8 + nt) * 64 + l) * 8);
        #pragma unroll
        for (int q = 0; q < 4; ++q)
            acc[nt] = __builtin_amdgcn_mfma_f32_16x16x32_bf16(a[q], b[q], acc[nt], 0, 0, 0);
    }

    __syncthreads();
    #pragma unroll
    for (int nt = 0; nt < 8; ++nt)
        #pragma unroll
        for (int r = 0; r < 4; ++r) {
            float v = acc[nt][r];
            float e = v > 0.f ? v : 1.6732632423543772f * expm1f(v);
            Al[(w * 16 + fq * 4 + r) * 136 + nt * 16 + fr] = f2bf(1.0507009873554805f * e);
        }
    __syncthreads();
    #pragma unroll
    for (int i = 0; i < 4; ++i) {
        int flat = i * 256 + t;
        int r = flat >> 4, c8 = flat & 15;
        *(short8*)(g + (size_t)(m0 + r) * 128 + c8 * 8) =
            *(const short8*)(Al + r * 136 + c8 * 8);
    }
}

// ---------------- K3a: split-K (4 chunks of 256) agg GEMM, bf16 A, fp32 partials ---
__global__ __launch_bounds__(256) void k_agg_mfma(
    const unsigned short* __restrict__ g, const unsigned short* __restrict__ agB,
    float* __restrict__ part)
{
    const int m0 = blockIdx.x * 64;
    const int kb = blockIdx.y;          // 0..3
    const int t  = threadIdx.x;
    __shared__ __align__(16) unsigned short Al[64 * 136];

    const int w = t >> 6, l = t & 63;
    const int fr = l & 15, fq = l >> 4;

    f32x4 acc[8];
    #pragma unroll
    for (int nt = 0; nt < 8; ++nt)
        #pragma unroll
        for (int r = 0; r < 4; ++r) acc[nt][r] = 0.f;

    #pragma unroll
    for (int h = 0; h < 2; ++h) {
        const int kc = kb * 2 + h;
        if (h) __syncthreads();
        #pragma unroll
        for (int i = 0; i < 4; ++i) {
            int flat = i * 256 + t;
            int r = flat >> 4, c8 = flat & 15;
            *(short8*)(Al + r * 136 + c8 * 8) =
                *(const short8*)(g + (size_t)(m0 + r) * 1024 + kc * 128 + c8 * 8);
        }
        __syncthreads();

        short8 a[4];
        #pragma unroll
        for (int q = 0; q < 4; ++q)
            a[q] = *(const short8*)(Al + (w * 16 + fr) * 136 + q * 32 + fq * 8);

        const unsigned short* Bb = agB + (size_t)kc * 16384;
        #pragma unroll 2
        for (int nt = 0; nt < 8; ++nt) {
            short8 b[4];
            #pragma unroll
            for (int q = 0; q < 4; ++q)
                b[q] = *(const short8*)(Bb + ((size_t)(q * 8 + nt) * 64 + l) * 8);
            #pragma unroll
            for (int q = 0; q < 4; ++q)
                acc[nt] = __builtin_amdgcn_mfma_f32_16x16x32_bf16(a[q], b[q], acc[nt], 0, 0, 0);
        }
    }

    float* Cb = part + (size_t)kb * NKP * 128 + (size_t)m0 * 128;
    #pragma unroll
    for (int nt = 0; nt < 8; ++nt)
        #pragma unroll
        for (int r = 0; r < 4; ++r)
            Cb[(size_t)(w * 16 + fq * 4 + r) * 128 + nt * 16 + fr] = acc[nt][r];
}

// ---------------- K3b: reduce 4 partials + L2 normalize ----------------
__global__ __launch_bounds__(256) void k_rn(const float* __restrict__ part,
                                            float* __restrict__ out)
{
    const int t = threadIdx.x;
    const int wv = t >> 6, l = t & 63;
    const int r = blockIdx.x * 4 + wv;
    float v0 = 0.f, v1 = 0.f;
    #pragma unroll
    for (int kc = 0; kc < 4; ++kc) {
        float2 v = *(const float2*)(part + ((size_t)kc * NKP + r) * 128 + 2 * l);
        v0 += v.x; v1 += v.y;
    }
    float s = v0 * v0 + v1 * v1;
    #pragma unroll
    for (int m = 32; m; m >>= 1) s += __shfl_xor(s, m);
    float inv = 1.f / fmaxf(sqrtf(s), 1e-12f);
    float2 o = {v0 * inv, v1 * inv};
    *(float2*)(out + (size_t)r * 128 + 2 * l) = o;
}

// ================= legacy fallback path (small ws) =================
__global__ __launch_bounds__(128) void k_sample(
    const float* __restrict__ x,  const float* __restrict__ kp,
    const float* __restrict__ w1, const float* __restrict__ b1,
    const float* __restrict__ w2, const float* __restrict__ b2,
    float* __restrict__ feats)
{
    const int n  = blockIdx.x;
    const int bi = n / NK;
    const int t  = threadIdx.x;

    __shared__ __align__(16) float patch[CH * 9];
    __shared__ float red[16 * 8];
    __shared__ float o1[16];
    __shared__ float offv[16];

    const float kx  = kp[(size_t)n * 2 + 0];
    const float ky  = kp[(size_t)n * 2 + 1];
    const float kwx = (kx * 0.5f + 0.5f) * (float)(WW - 1);
    const float kwy = (ky * 0.5f + 0.5f) * (float)(HH - 1);
    const int kwlx = (int)kwx;
    const int kwly = (int)kwy;
    int cx = (int)((float)kwlx - 0.5f);
    int cy = (int)((float)kwly - 0.5f);
    cx = min(max(cx, 0), WW - 1 - 3);
    cy = min(max(cy, 0), HH - 1 - 3);

    const float* xb = x + ((size_t)bi * CH + t) * HWSZ;
    {
        const float* p0 = xb + cy * WW + cx;
        #pragma unroll
        for (int i = 0; i < 3; ++i) {
            patch[t * 9 + i * 3 + 0] = p0[i * WW + 0];
            patch[t * 9 + i * 3 + 1] = p0[i * WW + 1];
            patch[t * 9 + i * 3 + 2] = p0[i * WW + 2];
        }
    }
    __syncthreads();
    {
        const int o = t & 15, g = t >> 4;
        const float4* wp = (const float4*)(w1 + o * 1152 + g * 144);
        const float4* pp = (const float4*)(patch + g * 144);
        float s = 0.f;
        #pragma unroll
        for (int q = 0; q < 36; ++q) {
            float4 wv = wp[q];
            float4 pv = pp[q];
            s = fmaf(wv.x, pv.x, fmaf(wv.y, pv.y, fmaf(wv.z, pv.z, fmaf(wv.w, pv.w, s))));
        }
        red[o * 8 + g] = s;
    }
    __syncthreads();
    if (t < 16) {
        float s = b1[t];
        #pragma unroll
        for (int g = 0; g < 8; ++g) s += red[t * 8 + g];
        o1[t] = fmaxf(s, 0.f);
    }
    __syncthreads();
    if (t < 16) {
        float s = b2[t];
        #pragma unroll
        for (int j = 0; j < 16; ++j) s = fmaf(o1[j], w2[t * 16 + j], s);
        offv[t] = fminf(fmaxf(s, -80.f), 80.f);
    }
    __syncthreads();

    #pragma unroll
    for (int p = 0; p < NPOS; ++p) {
        const float px = kwx + offv[p];
        const float py = kwy + offv[8 + p];
        const float x0 = floorf(px), y0 = floorf(py);
        const float wx = px - x0, wy = py - y0;
        float acc = 0.f;
        #pragma unroll
        for (int dy = 0; dy < 2; ++dy) {
            const float yc = y0 + (float)dy;
            const bool vy = (yc >= 0.f) && (yc <= (float)(HH - 1));
            const int  yi = (int)fminf(fmaxf(yc, 0.f), (float)(HH - 1));
            const float wyv = dy ? wy : (1.f - wy);
            #pragma unroll
            for (int dx = 0; dx < 2; ++dx) {
                const float xc = x0 + (float)dx;
                const bool vx = (xc >= 0.f) && (xc <= (float)(WW - 1));
                const int  xi = (int)fminf(fmaxf(xc, 0.f), (float)(WW - 1));
                const float wxv = dx ? wx : (1.f - wx);
                float v = xb[yi * WW + xi];
                v = (vx && vy) ? v : 0.f;
                acc = fmaf(v, wxv * wyv, acc);
            }
        }
        feats[((size_t)n * 8 + p) * CH + t] = acc;
    }
}

__global__ __launch_bounds__(256) void k_sf_legacy(float* __restrict__ gbuf,
                                                   const float* __restrict__ sfT)
{
    const int m0 = blockIdx.x * 64;
    const int t  = threadIdx.x;
    __shared__ __align__(16) float AT[128 * 68];

    #pragma unroll
    for (int i = 0; i < 32; ++i) {
        int flat = i * 256 + t;
        int mm = flat >> 7, kk = flat & 127;
        AT[kk * 68 + mm] = gbuf[(size_t)(m0 + mm) * 128 + kk];
    }
    __syncthreads();

    const int tx = t & 31, ty = t >> 5;
    const int d0 = tx * 4, mb = ty * 8;
    float acc[8][4];
    #pragma unroll
    for (int i = 0; i < 8; ++i)
        #pragma unroll
        for (int j = 0; j < 4; ++j) acc[i][j] = 0.f;

    #pragma unroll 4
    for (int k = 0; k < 128; ++k) {
        float4 a0 = *(const float4*)(AT + k * 68 + mb);
        float4 a1 = *(const float4*)(AT + k * 68 + mb + 4);
        float4 bq = *(const float4*)(sfT + k * 128 + d0);
        float a[8] = {a0.x, a0.y, a0.z, a0.w, a1.x, a1.y, a1.z, a1.w};
        float b4[4] = {bq.x, bq.y, bq.z, bq.w};
        #pragma unroll
        for (int i = 0; i < 8; ++i)
            #pragma unroll
            for (int j = 0; j < 4; ++j)
                acc[i][j] = fmaf(a[i], b4[j], acc[i][j]);
    }

    #pragma unroll
    for (int i = 0; i < 8; ++i) {
        float4 o;
        float* ov = &o.x;
        #pragma unroll
        for (int j = 0; j < 4; ++j) {
            float v = acc[i][j];
            float r = v > 0.f ? v : 1.6732632423543772f * expm1f(v);
            ov[j] = 1.0507009873554805f * r;
        }
        *(float4*)(gbuf + (size_t)(m0 + mb + i) * 128 + d0) = o;
    }
}

__global__ __launch_bounds__(256) void k_agg_mono(const float* __restrict__ gbuf,
                                                  const float* __restrict__ aggw,
                                                  float* __restrict__ out)
{
    const int m0 = blockIdx.x * 64;
    const int t  = threadIdx.x;
    __shared__ __align__(16) float AT[128 * 68];

    const int tx = t & 31, ty = t >> 5;
    const int d0 = tx * 4, mb = ty * 8;
    float acc[8][4];
    #pragma unroll
    for (int i = 0; i < 8; ++i)
        #pragma unroll
        for (int j = 0; j < 4; ++j) acc[i][j] = 0.f;

    for (int kc = 0; kc < 8; ++kc) {
        __syncthreads();
        #pragma unroll
        for (int i = 0; i < 32; ++i) {
            int flat = i * 256 + t;
            int mm = flat >> 7, kk = flat & 127;
            AT[kk * 68 + mm] = gbuf[(size_t)(m0 + mm) * 1024 + kc * 128 + kk];
        }
        __syncthreads();
        #pragma unroll 4
        for (int kk = 0; kk < 128; ++kk) {
            float4 a0 = *(const float4*)(AT + kk * 68 + mb);
            float4 a1 = *(const float4*)(AT + kk * 68 + mb + 4);
            float4 bq = *(const float4*)(aggw + (size_t)(kc * 128 + kk) * 128 + d0);
            float a[8] = {a0.x, a0.y, a0.z, a0.w, a1.x, a1.y, a1.z, a1.w};
            float b4[4] = {bq.x, bq.y, bq.z, bq.w};
            #pragma unroll
            for (int i = 0; i < 8; ++i)
                #pragma unroll
                for (int j = 0; j < 4; ++j)
                    acc[i][j] = fmaf(a[i], b4[j], acc[i][j]);
        }
    }

    #pragma unroll
    for (int i = 0; i < 8; ++i) {
        float s = acc[i][0] * acc[i][0] + acc[i][1] * acc[i][1]
                + acc[i][2] * acc[i][2] + acc[i][3] * acc[i][3];
        #pragma unroll
        for (int m = 16; m; m >>= 1) s += __shfl_xor(s, m);
        const float inv = 1.f / fmaxf(sqrtf(s), 1e-12f);
        float4 o = {acc[i][0] * inv, acc[i][1] * inv, acc[i][2] * inv, acc[i][3] * inv};
        *(float4*)(out + (size_t)(m0 + mb + i) * 128 + d0) = o;
    }
}

extern "C" void kernel_launch(void* const* d_in, const int* in_sizes, int n_in,
                              void* d_out, int out_size, void* d_ws, size_t ws_size,
                              hipStream_t stream)
{
    const float* x   = (const float*)d_in[0];
    const float* kp  = (const float*)d_in[1];
    const float* w1  = (const float*)d_in[2];
    const float* b1  = (const float*)d_in[3];
    const float* w2  = (const float*)d_in[4];
    const float* b2  = (const float*)d_in[5];
    const float* sfw = (const float*)d_in[6];
    const float* agg = (const float*)d_in[7];
    float* out = (float*)d_out;

    if (ws_size < WS_MIN) return;

    char*  ws    = (char*)d_ws;
    unsigned short* fb = (unsigned short*)ws;           // feats bf16 [128000][128]
    float* pos   = (float*)(ws + OFF_POS);              // [16000][8][2]
    float* sfT   = (float*)(ws + OFF_SFT);
    float* w1T   = (float*)(ws + OFF_W1T);
    float* xcl   = (float*)(ws + OFF_XCL);              // NHWC x
    float* part  = (float*)(ws + OFF_XCL);              // aliases xcl (dead after gather)
    unsigned short* g   = (unsigned short*)(ws + OFF_G);  // aliases xcl tail
    unsigned short* sfB = (unsigned short*)(ws + OFF_SFB);
    unsigned short* agB = (unsigned short*)(ws + OFF_AGB);

    k_prep<<<712, 256, 0, stream>>>(sfw, w1, agg, sfT, w1T, sfB, agB);

    if (ws_size >= WS_FULL) {
        dim3 grid(HWSZ / 32, CH / 32, BB), blk(32, 8);
        k_tr      <<<grid, blk, 0, stream>>>(x, xcl);
        k_offsets2<<<NKP / 16, 256, 0, stream>>>(xcl, kp, w1T, b1, w2, b2, pos);
        k_gather  <<<4000, 256, 0, stream>>>(xcl, pos, fb);
        k_sf_mfma <<<2000, 256, 0, stream>>>(fb, sfB, g);
        k_agg_mfma<<<dim3(250, 4), 256, 0, stream>>>(g, agB, part);
        k_rn      <<<4000, 256, 0, stream>>>(part, out);
    } else {
        float* feats = (float*)ws;
        k_sample   <<<NKP, 128, 0, stream>>>(x, kp, w1, b1, w2, b2, feats);
        k_sf_legacy<<<2000, 256, 0, stream>>>(feats, sfT);
        k_agg_mono <<<250,  256, 0, stream>>>(feats, agg, out);
    }
}